// Round 20
// baseline (771.489 us; speedup 1.0000x reference)
//
#include <hip/hip_runtime.h>
#include <stdint.h>

typedef __attribute__((ext_vector_type(8))) short bf16x8;
typedef __attribute__((ext_vector_type(4))) float f32x4;

#define N_NODES 8192
#define E_EDGES 163840
#define NGRAPH  32

#define INV_SQRT30 0.18257419f
#define SH0C       0.22360680f   /* 1/sqrt(20) */
#define SQRT3C     1.73205081f
#define INV_SQRT3  0.57735027f
#define INV_SQRT10 0.31622777f
#define SQ2C       0.70710678f

// ---------------- workspace layout (bytes) ----------------
enum : unsigned {
  OFF_W1P1 = 0u,       OFF_W2P1 = 65536u,   OFF_W3P1 = 589824u,  OFF_W4P1 = 655360u,
  OFF_W1P2 = 851968u,  OFF_W2P2 = 917504u,  OFF_W3P2 = 1441792u, OFF_W4P2 = 1507328u,
  OFF_B1P1 = 1515520u, OFF_B2P1 = 1517568u, OFF_B3P1 = 1519616u, OFF_B4P1 = 1519872u,
  OFF_B1P2 = 1526016u, OFF_B2P2 = 1528064u, OFF_B3P2 = 1530112u, OFF_B4P2 = 1530368u,
  OFF_HN   = 1530624u, // [8192][32] f32
  OFF_H2   = 2579200u, // [8192][64] f32
  OFF_AGG  = 4676352u, // [8192][70] f32
  OFF_AGG2 = 6970112u, // [8192] f32
  OFF_GSUM = 7002880u, // [32] f32
  OFF_ZEND = 7003008u,
  OFF_SHL  = 7003136u,  // [E][3] f32
  OFF_BAS  = 8969216u,  // [E][64] bf16 (linear)
  OFF_W4N1 = 29940736u, // 30 x 8 x 1KB
  OFF_X3   = 30186496u  // [E][64] bf16
};

__device__ __forceinline__ uint16_t f2bf(float f){
  union { float f; uint32_t u; } v; v.f = f;
  uint32_t r = v.u + 0x7fffu + ((v.u >> 16) & 1u);
  return (uint16_t)(r >> 16);
}
__device__ __forceinline__ float swishf(float x){ return x / (1.f + __expf(-x)); }

// ---------------- weight pre-pack (f32 src -> bf16 MFMA B-fragment order) ----------------
__device__ __forceinline__ void pack_mat(const float* __restrict__ src, int K, int N, int NP,
                                         uint16_t* __restrict__ dst, int t)
{
  int lane = t & 63;
  int tile = t >> 6;
  int NT = NP >> 4;
  int nn = tile % NT, kk = tile / NT;
  int k0 = kk*32 + ((lane >> 4) << 3);
  int n  = nn*16 + (lane & 15);
  union { short s[8]; bf16x8 v; } tmp;
#pragma unroll
  for (int b = 0; b < 8; ++b) {
    int k = k0 + b;
    tmp.s[b] = (k < K && n < N) ? (short)f2bf(src[(size_t)k*N + n]) : (short)0;
  }
  *reinterpret_cast<bf16x8*>(dst + (size_t)t*8) = tmp.v;
}

// W4' pack for tp1-as-GEMM
__device__ __forceinline__ void pack_w4n(const float* __restrict__ w4, const float* __restrict__ b4,
                                         uint16_t* __restrict__ dst, int t)
{
  int lane = t & 63;
  int tile = t >> 6;           // 0..239
  int u = tile >> 3, j = tile & 7;
  int kk = j >> 2, nn = j & 3;
  int k0 = kk*32 + ((lane >> 4) << 3);
  int n  = nn*16 + (lane & 15);
  union { short s[8]; bf16x8 v; } tmp;
#pragma unroll
  for (int b = 0; b < 8; ++b) {
    int k = k0 + b;
    float val = 0.f;
    if (n < 50) {
      int cg = (n < 40) ? (u*40 + n) : (1200 + u*10 + (n - 40));
      if (k < 50) val = w4[(size_t)k*1500 + cg];
      else if (k == 63) val = b4[cg];
    }
    tmp.s[b] = (short)f2bf(val);
  }
  *reinterpret_cast<bf16x8*>(dst + (size_t)t*8) = tmp.v;
}

__global__ void prep_kernel(const float* w1a, const float* w2a, const float* w3a, const float* w4a,
                            const float* w1b, const float* w2b, const float* w3b, const float* w4b,
                            const float* b1a, const float* b2a, const float* b3a, const float* b4a,
                            const float* b1b, const float* b2b, const float* b3b, const float* b4b,
                            const float* emb, const int* z, char* ws)
{
  int t = blockIdx.x * 256 + threadIdx.x;
  if      (t < 4096)   pack_mat(w1a, 40, 500, 512,  (uint16_t*)(ws + OFF_W1P1), t);
  else if (t < 36864)  pack_mat(w2a, 500,500, 512,  (uint16_t*)(ws + OFF_W2P1), t - 4096);
  else if (t < 40960)  pack_mat(w3a, 500, 50, 64,   (uint16_t*)(ws + OFF_W3P1), t - 36864);
  else if (t < 45056)  { /* spare */ }
  else if (t < 49152)  pack_mat(w1b, 40, 500, 512,  (uint16_t*)(ws + OFF_W1P2), t - 45056);
  else if (t < 81920)  pack_mat(w2b, 500,500, 512,  (uint16_t*)(ws + OFF_W2P2), t - 49152);
  else if (t < 86016)  pack_mat(w3b, 500, 50, 64,   (uint16_t*)(ws + OFF_W3P2), t - 81920);
  else if (t < 86528)  pack_mat(w4b, 50,  40, 64,   (uint16_t*)(ws + OFF_W4P2), t - 86016);
  else if (t < 90304) {
    int loc = t - 86528;
    const float* src; float* dst; int realN;
    if      (loc < 512)  { src=b1a; dst=(float*)(ws+OFF_B1P1); realN=500; }
    else if (loc < 1024) { src=b2a; dst=(float*)(ws+OFF_B2P1); realN=500;  loc -= 512;  }
    else if (loc < 1088) { src=b3a; dst=(float*)(ws+OFF_B3P1); realN=50;   loc -= 1024; }
    else if (loc < 2624) { src=b4a; dst=(float*)(ws+OFF_B4P1); realN=1500; loc -= 1088; }
    else if (loc < 3136) { src=b1b; dst=(float*)(ws+OFF_B1P2); realN=500;  loc -= 2624; }
    else if (loc < 3648) { src=b2b; dst=(float*)(ws+OFF_B2P2); realN=500;  loc -= 3136; }
    else if (loc < 3712) { src=b3b; dst=(float*)(ws+OFF_B3P2); realN=50;   loc -= 3648; }
    else                 { src=b4b; dst=(float*)(ws+OFF_B4P2); realN=40;   loc -= 3712; }
    dst[loc] = (loc < realN) ? src[loc] : 0.f;
  }
  else if (t < 352448) {
    int i = t - 90304;
    int n = i >> 5, u = i & 31;
    float v = 0.f;
    if (u < 30) v = emb[(size_t)z[n]*30 + u] * INV_SQRT30;
    ((float*)(ws + OFF_HN))[i] = v;
  }
  else if (t < 367808) {
    pack_w4n(w4a, b4a, (uint16_t*)(ws + OFF_W4N1), t - 352448);
  }
}

// ---------------- edge meta ----------------
__global__ void edge_meta(const float* __restrict__ pos, const int* __restrict__ eidx,
                          uint16_t* __restrict__ basis, float* __restrict__ shl)
{
  int e = blockIdx.x * 256 + threadIdx.x;
  if (e >= E_EDGES) return;
  int rn = eidx[e], cn = eidx[E_EDGES + e];
  float ax = pos[rn*3+0] - pos[cn*3+0];
  float ay = pos[rn*3+1] - pos[cn*3+1];
  float az = pos[rn*3+2] - pos[cn*3+2];
  float rr = sqrtf(ax*ax + ay*ay + az*az + 1e-12f);
  float s = SQRT3C * SH0C / rr;
  shl[e*3+0] = ax*s; shl[e*3+1] = ay*s; shl[e*3+2] = az*s;
#pragma unroll
  for (int j = 0; j < 8; ++j) {
    union { short s[8]; bf16x8 v; } tmp;
#pragma unroll
    for (int b = 0; b < 8; ++b) {
      int c = j*8 + b;
      float vv = 0.f;
      if (c < 40) { float t = rr*3.9f - (float)c; vv = __expf(-t*t); }
      tmp.s[b] = (short)f2bf(vv);
    }
    *reinterpret_cast<bf16x8*>(basis + (size_t)e*64 + j*8) = tmp.v;
  }
}

// ---------------- fused MLP, 32-row tiles, 4 waves, 4 blocks/CU ----------------
__global__ __launch_bounds__(256, 4)
void fused_mlp(const uint16_t* __restrict__ basis,
               const uint16_t* __restrict__ W1p, const float* __restrict__ b1,
               const uint16_t* __restrict__ W2p, const float* __restrict__ b2,
               const uint16_t* __restrict__ W3p, const float* __restrict__ b3,
               uint16_t* __restrict__ x3)
{
  __shared__ __align__(16) char actb[32768];   // [32][512] bf16, XOR-swizzled

  const int tid = threadIdx.x, lane = tid & 63, wv = tid >> 6;  // 4 waves
  const int m0 = blockIdx.x * 32;
  const int r = lane & 15, q = lane >> 4;

  const bf16x8* __restrict__ W1v = (const bf16x8*)W1p;
  const bf16x8* __restrict__ W2v = (const bf16x8*)W2p;
  const bf16x8* __restrict__ W3v = (const bf16x8*)W3p;

  f32x4 zv = {0.f, 0.f, 0.f, 0.f};

  // ---- stage 1: act1 = swish(basis @ W1 + b1); A direct from global; wave: 32 x 128 ----
  {
    f32x4 acc[2][8];
#pragma unroll
    for (int a = 0; a < 2; ++a)
#pragma unroll
      for (int c = 0; c < 8; ++c) acc[a][c] = zv;
#pragma unroll
    for (int ks = 0; ks < 2; ++ks) {
      bf16x8 af[2];
#pragma unroll
      for (int rb = 0; rb < 2; ++rb) {
        int row = m0 + rb*16 + r;
        af[rb] = *reinterpret_cast<const bf16x8*>((const char*)basis + (size_t)row*128 + ks*64 + q*16);
      }
#pragma unroll
      for (int c4 = 0; c4 < 4; ++c4) {
        bf16x8 bfr[2];
#pragma unroll
        for (int j = 0; j < 2; ++j)
          bfr[j] = W1v[(size_t)((ks*32 + wv*8 + c4*2 + j)*64 + lane)];
#pragma unroll
        for (int j = 0; j < 2; ++j)
#pragma unroll
          for (int rb = 0; rb < 2; ++rb)
            acc[rb][c4*2 + j] = __builtin_amdgcn_mfma_f32_16x16x32_bf16(af[rb], bfr[j], acc[rb][c4*2 + j], 0, 0, 0);
      }
    }
#pragma unroll
    for (int nt = 0; nt < 8; ++nt) {
      int col = wv*128 + nt*16 + r;
      float bs = b1[col];
#pragma unroll
      for (int rb = 0; rb < 2; ++rb)
#pragma unroll
        for (int i = 0; i < 4; ++i) {
          int row = rb*16 + q*4 + i;
          int off = row*1024 + ((col*2) ^ ((row & 7) << 4));
          *(uint16_t*)(&actb[off]) = f2bf(swishf(acc[rb][nt][i] + bs));
        }
    }
  }
  __syncthreads();

  // ---- stage 2: act2 = swish(act1 @ W2 + b2); wave: 32 x 128 ----
  {
    f32x4 acc[2][8];
#pragma unroll
    for (int a = 0; a < 2; ++a)
#pragma unroll
      for (int c = 0; c < 8; ++c) acc[a][c] = zv;
#pragma unroll 1
    for (int ks = 0; ks < 16; ++ks) {
      bf16x8 af[2];
#pragma unroll
      for (int rb = 0; rb < 2; ++rb) {
        int row = rb*16 + r;
        int off = row*1024 + ((ks*64 + q*16) ^ ((row & 7) << 4));
        af[rb] = *reinterpret_cast<const bf16x8*>(&actb[off]);
      }
#pragma unroll
      for (int c4 = 0; c4 < 4; ++c4) {
        bf16x8 bfr[2];
#pragma unroll
        for (int j = 0; j < 2; ++j)
          bfr[j] = W2v[(size_t)((ks*32 + wv*8 + c4*2 + j)*64 + lane)];
#pragma unroll
        for (int j = 0; j < 2; ++j)
#pragma unroll
          for (int rb = 0; rb < 2; ++rb)
            acc[rb][c4*2 + j] = __builtin_amdgcn_mfma_f32_16x16x32_bf16(af[rb], bfr[j], acc[rb][c4*2 + j], 0, 0, 0);
      }
    }
    __syncthreads();   // all waves done READING act1
#pragma unroll
    for (int nt = 0; nt < 8; ++nt) {
      int col = wv*128 + nt*16 + r;
      float bs = b2[col];
#pragma unroll
      for (int rb = 0; rb < 2; ++rb)
#pragma unroll
        for (int i = 0; i < 4; ++i) {
          int row = rb*16 + q*4 + i;
          int off = row*1024 + ((col*2) ^ ((row & 7) << 4));
          *(uint16_t*)(&actb[off]) = f2bf(swishf(acc[rb][nt][i] + bs));
        }
    }
  }
  __syncthreads();

  // ---- stage 3: x3 = swish(act2 @ W3 + b3), col63 := 1; wave: 1 ntile x 2 rowblocks ----
  {
    f32x4 acc[2];
    acc[0] = zv; acc[1] = zv;
#pragma unroll 2
    for (int ks = 0; ks < 16; ++ks) {
      bf16x8 bb = W3v[(size_t)((ks*4 + wv)*64 + lane)];
#pragma unroll
      for (int rb = 0; rb < 2; ++rb) {
        int row = rb*16 + r;
        int off = row*1024 + ((ks*64 + q*16) ^ ((row & 7) << 4));
        bf16x8 a = *reinterpret_cast<const bf16x8*>(&actb[off]);
        acc[rb] = __builtin_amdgcn_mfma_f32_16x16x32_bf16(a, bb, acc[rb], 0, 0, 0);
      }
    }
    int col = wv*16 + r;
    float bs = b3[col];
#pragma unroll
    for (int rb = 0; rb < 2; ++rb)
#pragma unroll
      for (int i = 0; i < 4; ++i) {
        int row = m0 + rb*16 + q*4 + i;
        float v = swishf(acc[rb][i] + bs);
        if (col == 63) v = 1.f;
        x3[(size_t)row*64 + col] = f2bf(v);
      }
  }
}

// ---------------- TP layer 1 as scaled GEMM ----------------
__global__ __launch_bounds__(512, 4)
void tp1_gemm(const uint16_t* __restrict__ x3, const char* __restrict__ ws,
              const int* __restrict__ eidx, float* __restrict__ agg)
{
  __shared__ __align__(16) uint16_t Wst[2][4096];
  __shared__ float xjs[64*32];
  __shared__ float mbuf[64*64];
  __shared__ float shls[64*3];
  __shared__ int   rowl[64];
  __shared__ int   coll[64];

  const float* hN  = (const float*)(ws + OFF_HN);
  const float* shl = (const float*)(ws + OFF_SHL);
  const char*  W4n = (const char*)(ws + OFF_W4N1);

  const int tid = threadIdx.x, lane = tid & 63, wv = tid >> 6;
  const int e0l = blockIdx.x * 64;
  const int r_ = lane & 15, q_ = lane >> 4;
  const int rowg = wv >> 1, colg = wv & 1;

  if (tid < 64) { rowl[tid] = eidx[e0l + tid]; coll[tid] = eidx[E_EDGES + e0l + tid]; }
  for (int i = tid; i < 192; i += 512) shls[i] = shl[(size_t)e0l*3 + i];
  __syncthreads();
  for (int i = tid; i < 64*32; i += 512) {
    int e = i >> 5, u = i & 31;
    xjs[i] = hN[(size_t)rowl[e]*32 + u];
  }

  bf16x8 a0, a1;
  {
    int row = e0l + rowg*16 + r_;
    const char* base = (const char*)x3 + (size_t)row*128 + q_*16;
    a0 = *reinterpret_cast<const bf16x8*>(base);
    a1 = *reinterpret_cast<const bf16x8*>(base + 64);
  }

  const char* srcW = W4n + ((size_t)(tid >> 6)*64 + lane)*16;
  auto stageW = [&](int buf, int u) {
    __builtin_amdgcn_global_load_lds((const __attribute__((address_space(1))) void*)(srcW + (size_t)u*8192),
        (__attribute__((address_space(3))) void*)(&Wst[buf][(size_t)tid*8]), 16, 0, 0);
  };

  f32x4 zv = {0.f, 0.f, 0.f, 0.f};
  f32x4 accF[2];
  accF[0] = zv; accF[1] = zv;

  stageW(0, 0);
  __syncthreads();

  const char* wb0 = (const char*)&Wst[0][0] + ((size_t)(colg*2)*64 + lane)*16;
  const char* wb1 = (const char*)&Wst[1][0] + ((size_t)(colg*2)*64 + lane)*16;

  int cur = 0;
#pragma unroll 1
  for (int u = 0; u < 30; ++u) {
    if (u + 1 < 30) stageW(cur ^ 1, u + 1);
    const char* wb = cur ? wb1 : wb0;
    bf16x8 b00 = *reinterpret_cast<const bf16x8*>(wb);
    bf16x8 b01 = *reinterpret_cast<const bf16x8*>(wb + 1024);
    bf16x8 b10 = *reinterpret_cast<const bf16x8*>(wb + 4096);
    bf16x8 b11 = *reinterpret_cast<const bf16x8*>(wb + 5120);
    f32x4 t0 = __builtin_amdgcn_mfma_f32_16x16x32_bf16(a0, b00, zv, 0, 0, 0);
    t0 = __builtin_amdgcn_mfma_f32_16x16x32_bf16(a1, b10, t0, 0, 0, 0);
    f32x4 t1 = __builtin_amdgcn_mfma_f32_16x16x32_bf16(a0, b01, zv, 0, 0, 0);
    t1 = __builtin_amdgcn_mfma_f32_16x16x32_bf16(a1, b11, t1, 0, 0, 0);
#pragma unroll
    for (int i = 0; i < 4; ++i) {
      float xv = xjs[(rowg*16 + q_*4 + i)*32 + u];
      accF[0][i] += xv * t0[i];
      accF[1][i] += xv * t1[i];
    }
    if (u + 1 < 30) {
      asm volatile("s_waitcnt vmcnt(0)" ::: "memory");
      __builtin_amdgcn_s_barrier();
      cur ^= 1;
    }
  }

#pragma unroll
  for (int nt = 0; nt < 2; ++nt)
#pragma unroll
    for (int i = 0; i < 4; ++i)
      mbuf[(rowg*16 + q_*4 + i)*64 + colg*32 + nt*16 + r_] = accF[nt][i];
  __syncthreads();

#pragma unroll 1
  for (int i = tid; i < 64*70; i += 512) {
    int e = i/70, c = i - e*70;
    float v;
    if (c < 40) v = mbuf[e*64 + c] * SH0C;
    else { int vv = (c - 40)/3, k = (c - 40) - vv*3; v = mbuf[e*64 + 40 + vv] * shls[e*3 + k]; }
    atomicAdd(&agg[(size_t)coll[e]*70 + c], v);
  }
}

// ---------------- TP layer 2 ----------------
__global__ __launch_bounds__(512, 2)
void tp2_kernel(const uint16_t* __restrict__ x3, const char* __restrict__ ws,
                const int* __restrict__ eidx, float* __restrict__ agg2)
{
  constexpr int P2 = 67;
  __shared__ float wbuf2[64 * P2];
  __shared__ float xjs[64*30];
  __shared__ float xjv[64*30];
  __shared__ float Db[64*10];
  __shared__ float shls[64*3];
  __shared__ int   rowl[64];
  __shared__ int   coll[64];

  const float* h2  = (const float*)(ws + OFF_H2);
  const float* shl = (const float*)(ws + OFF_SHL);
  const float* b4p = (const float*)(ws + OFF_B4P2);
  const bf16x8* __restrict__ bv4 = (const bf16x8*)(ws + OFF_W4P2);

  const int tid = threadIdx.x, lane = tid & 63, wv = tid >> 6;
  const int e0l = blockIdx.x * 64;
  const int r_ = lane & 15, q_ = lane >> 4;

  if (tid < 64) { rowl[tid] = eidx[e0l + tid]; coll[tid] = eidx[E_EDGES + e0l + tid]; }
  for (int i = tid; i < 192; i += 512) shls[i] = shl[(size_t)e0l*3 + i];
  __syncthreads();
  for (int i = tid; i < 64*60; i += 512) {
    int e = i/60, u = i - e*60;
    float v = h2[(size_t)rowl[e]*64 + u];
    if (u < 30) xjs[e*30 + u] = v; else xjv[e*30 + (u - 30)] = v;
  }
  __syncthreads();
  for (int i = tid; i < 640; i += 512) {
    int e = i/10, v = i - e*10;
    float d = 0.f;
#pragma unroll
    for (int m = 0; m < 3; ++m) d += xjv[e*30 + v*3 + m] * shls[e*3 + m];
    Db[i] = d * INV_SQRT3;
  }

  const int rbase = (wv >> 2)*2, nt4 = wv & 3;
  bf16x8 a4[2][2];
#pragma unroll
  for (int kk = 0; kk < 2; ++kk)
#pragma unroll
    for (int rbi = 0; rbi < 2; ++rbi) {
      int row = e0l + (rbase + rbi)*16 + r_;
      a4[kk][rbi] = *reinterpret_cast<const bf16x8*>((const char*)x3 + (size_t)row*128 + kk*64 + q_*16);
    }
  f32x4 acc[2];
  f32x4 zv = {0.f, 0.f, 0.f, 0.f};
  acc[0] = zv; acc[1] = zv;
#pragma unroll
  for (int kk = 0; kk < 2; ++kk) {
    bf16x8 b4 = bv4[(size_t)(kk*4 + nt4)*64 + lane];
#pragma unroll
    for (int rbi = 0; rbi < 2; ++rbi)
      acc[rbi] = __builtin_amdgcn_mfma_f32_16x16x32_bf16(a4[kk][rbi], b4, acc[rbi], 0, 0, 0);
  }
  __syncthreads();
  {
    int cg = nt4*16 + r_;
    float bs = b4p[cg];
#pragma unroll
    for (int rbi = 0; rbi < 2; ++rbi)
#pragma unroll
      for (int i2 = 0; i2 < 4; ++i2) {
        int e = (rbase + rbi)*16 + q_*4 + i2;
        wbuf2[e*P2 + cg] = acc[rbi][i2] + bs;
      }
  }
  __syncthreads();

  if (tid < 64) {
    int e = tid;
    float m = 0.f, m2 = 0.f;
#pragma unroll
    for (int c = 0; c < 30; ++c) m += xjs[e*30 + c] * wbuf2[e*P2 + c];
#pragma unroll
    for (int vv = 0; vv < 10; ++vv) m2 += Db[e*10 + vv] * wbuf2[e*P2 + 30 + vv];
    atomicAdd(&agg2[coll[e]], m * (SH0C * INV_SQRT30) + m2 * INV_SQRT10);
  }
}

// ---------------- node kernels ----------------
__global__ void node_mid(char* ws, const float* __restrict__ si1w)
{
  int nid = blockIdx.x * blockDim.x + threadIdx.x;
  if (nid >= N_NODES) return;
  const float* hN  = (const float*)(ws + OFF_HN)  + (size_t)nid*32;
  const float* agg = (const float*)(ws + OFF_AGG) + (size_t)nid*70;
  float* h2        = (float*)(ws + OFF_H2)        + (size_t)nid*64;

  float hn[30];
#pragma unroll
  for (int u = 0; u < 30; ++u) hn[u] = hN[u];

  float h1[70];
#pragma unroll 1
  for (int v = 0; v < 40; ++v) {
    float s = 0.f;
#pragma unroll
    for (int u = 0; u < 30; ++u) s += hn[u] * si1w[u*40 + v];
    h1[v] = SQ2C * (s + agg[v]);
  }
#pragma unroll
  for (int c = 40; c < 70; ++c) h1[c] = agg[c];

#pragma unroll
  for (int u = 0; u < 30; ++u) h2[u] = swishf(h1[u]);
#pragma unroll
  for (int v = 0; v < 10; ++v) {
    float g = 1.f / (1.f + __expf(-h1[30 + v]));
#pragma unroll
    for (int k = 0; k < 3; ++k) h2[30 + v*3 + k] = h1[40 + v*3 + k] * g;
  }
}

__global__ void node_final(char* ws, const float* __restrict__ si2w, const int* __restrict__ batch)
{
  __shared__ float ls[NGRAPH];
  if (threadIdx.x < NGRAPH) ls[threadIdx.x] = 0.f;
  __syncthreads();
  int nid = blockIdx.x * blockDim.x + threadIdx.x;
  if (nid < N_NODES) {
    const float* h2   = (const float*)(ws + OFF_H2) + (size_t)nid*64;
    const float* agg2 = (const float*)(ws + OFF_AGG2);
    float s2 = 0.f;
#pragma unroll
    for (int u = 0; u < 30; ++u) s2 += h2[u] * si2w[u];
    float val = SQ2C * (s2 * INV_SQRT30 + agg2[nid]);
    atomicAdd(&ls[batch[nid]], val);
  }
  __syncthreads();
  if (threadIdx.x < NGRAPH)
    atomicAdd(((float*)(ws + OFF_GSUM)) + threadIdx.x, ls[threadIdx.x]);
}

__global__ void write_out(const char* ws, float* out)
{
  int g = threadIdx.x;
  if (g < NGRAPH) out[g] = ((const float*)(ws + OFF_GSUM))[g];
}

// ---------------- launch ----------------
extern "C" void kernel_launch(void* const* d_in, const int* in_sizes, int n_in,
                              void* d_out, int out_size, void* d_ws, size_t ws_size,
                              hipStream_t stream)
{
  const float* pos  = (const float*)d_in[0];
  const float* emb  = (const float*)d_in[1];
  const float* si1w = (const float*)d_in[2];
  const float* si2w = (const float*)d_in[3];
  const float* w1a = (const float*)d_in[4];  const float* b1a = (const float*)d_in[5];
  const float* w2a = (const float*)d_in[6];  const float* b2a = (const float*)d_in[7];
  const float* w3a = (const float*)d_in[8];  const float* b3a = (const float*)d_in[9];
  const float* w4a = (const float*)d_in[10]; const float* b4a = (const float*)d_in[11];
  const float* w1b = (const float*)d_in[12]; const float* b1b = (const float*)d_in[13];
  const float* w2b = (const float*)d_in[14]; const float* b2b = (const float*)d_in[15];
  const float* w3b = (const float*)d_in[16]; const float* b3b = (const float*)d_in[17];
  const float* w4b = (const float*)d_in[18]; const float* b4b = (const float*)d_in[19];
  const int* z     = (const int*)d_in[20];
  const int* eidx  = (const int*)d_in[21];
  const int* batch = (const int*)d_in[22];
  char* ws = (char*)d_ws;

  uint16_t* basis = (uint16_t*)(ws + OFF_BAS);
  float*    shl   = (float*)(ws + OFF_SHL);
  uint16_t* x3    = (uint16_t*)(ws + OFF_X3);

  hipMemsetAsync(ws + OFF_AGG, 0, OFF_ZEND - OFF_AGG, stream);

  prep_kernel<<<1437, 256, 0, stream>>>(w1a, w2a, w3a, w4a, w1b, w2b, w3b, w4b,
                                        b1a, b2a, b3a, b4a, b1b, b2b, b3b, b4b,
                                        emb, z, ws);
  edge_meta<<<E_EDGES/256, 256, 0, stream>>>(pos, eidx, basis, shl);

  // ---- layer 1 ----
  fused_mlp<<<E_EDGES/32, 256, 0, stream>>>(basis,
      (const uint16_t*)(ws + OFF_W1P1), (const float*)(ws + OFF_B1P1),
      (const uint16_t*)(ws + OFF_W2P1), (const float*)(ws + OFF_B2P1),
      (const uint16_t*)(ws + OFF_W3P1), (const float*)(ws + OFF_B3P1), x3);
  tp1_gemm<<<E_EDGES/64, 512, 0, stream>>>(x3, ws, eidx, (float*)(ws + OFF_AGG));

  node_mid<<<N_NODES/256, 256, 0, stream>>>(ws, si1w);

  // ---- layer 2 ----
  fused_mlp<<<E_EDGES/32, 256, 0, stream>>>(basis,
      (const uint16_t*)(ws + OFF_W1P2), (const float*)(ws + OFF_B1P2),
      (const uint16_t*)(ws + OFF_W2P2), (const float*)(ws + OFF_B2P2),
      (const uint16_t*)(ws + OFF_W3P2), (const float*)(ws + OFF_B3P2), x3);
  tp2_kernel<<<E_EDGES/64, 512, 0, stream>>>(x3, ws, eidx, (float*)(ws + OFF_AGG2));

  node_final<<<N_NODES/256, 256, 0, stream>>>(ws, si2w, batch);
  write_out<<<1, 64, 0, stream>>>(ws, (float*)d_out);
}

// Round 21
// 620.775 us; speedup vs baseline: 1.2428x; 1.2428x over previous
//
#include <hip/hip_runtime.h>
#include <stdint.h>

typedef __attribute__((ext_vector_type(8))) short bf16x8;
typedef __attribute__((ext_vector_type(4))) float f32x4;

#define N_NODES 8192
#define E_EDGES 163840
#define NGRAPH  32

#define INV_SQRT30 0.18257419f
#define SH0C       0.22360680f   /* 1/sqrt(20) */
#define SQRT3C     1.73205081f
#define INV_SQRT3  0.57735027f
#define INV_SQRT10 0.31622777f
#define SQ2C       0.70710678f

// ---------------- workspace layout (bytes) ----------------
enum : unsigned {
  OFF_W1P1 = 0u,       OFF_W2P1 = 65536u,   OFF_W3P1 = 589824u,  OFF_W4P1 = 655360u,
  OFF_W1P2 = 851968u,  OFF_W2P2 = 917504u,  OFF_W3P2 = 1441792u, OFF_W4P2 = 1507328u,
  OFF_B1P1 = 1515520u, OFF_B2P1 = 1517568u, OFF_B3P1 = 1519616u, OFF_B4P1 = 1519872u,
  OFF_B1P2 = 1526016u, OFF_B2P2 = 1528064u, OFF_B3P2 = 1530112u, OFF_B4P2 = 1530368u,
  OFF_HN   = 1530624u, // [8192][32] f32
  OFF_H2   = 2579200u, // [8192][64] f32
  OFF_AGG  = 4676352u, // [8192][70] f32
  OFF_AGG2 = 6970112u, // [8192] f32
  OFF_GSUM = 7002880u, // [32] f32
  OFF_ZEND = 7003008u,
  OFF_SHL  = 7003136u,  // [E][3] f32
  OFF_BAS  = 8969216u,  // [E][64] bf16 (linear)
  OFF_W4N1 = 29940736u, // 30 x 8 x 1KB
  OFF_X3   = 30186496u  // [E][64] bf16
};

__device__ __forceinline__ uint16_t f2bf(float f){
  union { float f; uint32_t u; } v; v.f = f;
  uint32_t r = v.u + 0x7fffu + ((v.u >> 16) & 1u);
  return (uint16_t)(r >> 16);
}
__device__ __forceinline__ uint16_t f2bf_trunc(float f){
  union { float f; uint32_t u; } v; v.f = f;
  return (uint16_t)(v.u >> 16);
}
__device__ __forceinline__ float swishf(float x){ return x / (1.f + __expf(-x)); }

// ---------------- weight pre-pack (f32 src -> bf16 MFMA B-fragment order) ----------------
__device__ __forceinline__ void pack_mat(const float* __restrict__ src, int K, int N, int NP,
                                         uint16_t* __restrict__ dst, int t)
{
  int lane = t & 63;
  int tile = t >> 6;
  int NT = NP >> 4;
  int nn = tile % NT, kk = tile / NT;
  int k0 = kk*32 + ((lane >> 4) << 3);
  int n  = nn*16 + (lane & 15);
  union { short s[8]; bf16x8 v; } tmp;
#pragma unroll
  for (int b = 0; b < 8; ++b) {
    int k = k0 + b;
    tmp.s[b] = (k < K && n < N) ? (short)f2bf(src[(size_t)k*N + n]) : (short)0;
  }
  *reinterpret_cast<bf16x8*>(dst + (size_t)t*8) = tmp.v;
}

// W4' pack for tp1-as-GEMM
__device__ __forceinline__ void pack_w4n(const float* __restrict__ w4, const float* __restrict__ b4,
                                         uint16_t* __restrict__ dst, int t)
{
  int lane = t & 63;
  int tile = t >> 6;           // 0..239
  int u = tile >> 3, j = tile & 7;
  int kk = j >> 2, nn = j & 3;
  int k0 = kk*32 + ((lane >> 4) << 3);
  int n  = nn*16 + (lane & 15);
  union { short s[8]; bf16x8 v; } tmp;
#pragma unroll
  for (int b = 0; b < 8; ++b) {
    int k = k0 + b;
    float val = 0.f;
    if (n < 50) {
      int cg = (n < 40) ? (u*40 + n) : (1200 + u*10 + (n - 40));
      if (k < 50) val = w4[(size_t)k*1500 + cg];
      else if (k == 63) val = b4[cg];
    }
    tmp.s[b] = (short)f2bf(val);
  }
  *reinterpret_cast<bf16x8*>(dst + (size_t)t*8) = tmp.v;
}

__global__ void prep_kernel(const float* w1a, const float* w2a, const float* w3a, const float* w4a,
                            const float* w1b, const float* w2b, const float* w3b, const float* w4b,
                            const float* b1a, const float* b2a, const float* b3a, const float* b4a,
                            const float* b1b, const float* b2b, const float* b3b, const float* b4b,
                            const float* emb, const int* z, char* ws)
{
  int t = blockIdx.x * 256 + threadIdx.x;
  if      (t < 4096)   pack_mat(w1a, 40, 500, 512,  (uint16_t*)(ws + OFF_W1P1), t);
  else if (t < 36864)  pack_mat(w2a, 500,500, 512,  (uint16_t*)(ws + OFF_W2P1), t - 4096);
  else if (t < 40960)  pack_mat(w3a, 500, 50, 64,   (uint16_t*)(ws + OFF_W3P1), t - 36864);
  else if (t < 45056)  { /* spare */ }
  else if (t < 49152)  pack_mat(w1b, 40, 500, 512,  (uint16_t*)(ws + OFF_W1P2), t - 45056);
  else if (t < 81920)  pack_mat(w2b, 500,500, 512,  (uint16_t*)(ws + OFF_W2P2), t - 49152);
  else if (t < 86016)  pack_mat(w3b, 500, 50, 64,   (uint16_t*)(ws + OFF_W3P2), t - 81920);
  else if (t < 86528)  pack_mat(w4b, 50,  40, 64,   (uint16_t*)(ws + OFF_W4P2), t - 86016);
  else if (t < 90304) {
    int loc = t - 86528;
    const float* src; float* dst; int realN;
    if      (loc < 512)  { src=b1a; dst=(float*)(ws+OFF_B1P1); realN=500; }
    else if (loc < 1024) { src=b2a; dst=(float*)(ws+OFF_B2P1); realN=500;  loc -= 512;  }
    else if (loc < 1088) { src=b3a; dst=(float*)(ws+OFF_B3P1); realN=50;   loc -= 1024; }
    else if (loc < 2624) { src=b4a; dst=(float*)(ws+OFF_B4P1); realN=1500; loc -= 1088; }
    else if (loc < 3136) { src=b1b; dst=(float*)(ws+OFF_B1P2); realN=500;  loc -= 2624; }
    else if (loc < 3648) { src=b2b; dst=(float*)(ws+OFF_B2P2); realN=500;  loc -= 3136; }
    else if (loc < 3712) { src=b3b; dst=(float*)(ws+OFF_B3P2); realN=50;   loc -= 3648; }
    else                 { src=b4b; dst=(float*)(ws+OFF_B4P2); realN=40;   loc -= 3712; }
    dst[loc] = (loc < realN) ? src[loc] : 0.f;
  }
  else if (t < 352448) {
    int i = t - 90304;
    int n = i >> 5, u = i & 31;
    float v = 0.f;
    if (u < 30) v = emb[(size_t)z[n]*30 + u] * INV_SQRT30;
    ((float*)(ws + OFF_HN))[i] = v;
  }
  else if (t < 367808) {
    pack_w4n(w4a, b4a, (uint16_t*)(ws + OFF_W4N1), t - 352448);
  }
}

// ---------------- edge meta ----------------
__global__ void edge_meta(const float* __restrict__ pos, const int* __restrict__ eidx,
                          uint16_t* __restrict__ basis, float* __restrict__ shl)
{
  int e = blockIdx.x * 256 + threadIdx.x;
  if (e >= E_EDGES) return;
  int rn = eidx[e], cn = eidx[E_EDGES + e];
  float ax = pos[rn*3+0] - pos[cn*3+0];
  float ay = pos[rn*3+1] - pos[cn*3+1];
  float az = pos[rn*3+2] - pos[cn*3+2];
  float rr = sqrtf(ax*ax + ay*ay + az*az + 1e-12f);
  float s = SQRT3C * SH0C / rr;
  shl[e*3+0] = ax*s; shl[e*3+1] = ay*s; shl[e*3+2] = az*s;
#pragma unroll
  for (int j = 0; j < 8; ++j) {
    union { short s[8]; bf16x8 v; } tmp;
#pragma unroll
    for (int b = 0; b < 8; ++b) {
      int c = j*8 + b;
      float vv = 0.f;
      if (c < 40) { float t = rr*3.9f - (float)c; vv = __expf(-t*t); }
      tmp.s[b] = (short)f2bf(vv);
    }
    *reinterpret_cast<bf16x8*>(basis + (size_t)e*64 + j*8) = tmp.v;
  }
}

// ---------------- fused MLP, 64-row tiles, (512,2) no-spill envelope ----------------
__global__ __launch_bounds__(512, 2)
void fused_mlp(const uint16_t* __restrict__ basis,
               const uint16_t* __restrict__ W1p, const float* __restrict__ b1,
               const uint16_t* __restrict__ W2p, const float* __restrict__ b2,
               const uint16_t* __restrict__ W3p, const float* __restrict__ b3,
               uint16_t* __restrict__ x3)
{
  __shared__ __align__(16) char actb[65536];   // [64][512] bf16, XOR-swizzled

  const int tid = threadIdx.x, lane = tid & 63, wv = tid >> 6;
  const int m0 = blockIdx.x * 64;
  const int r = lane & 15, q = lane >> 4;

  const bf16x8* __restrict__ W1v = (const bf16x8*)W1p;
  const bf16x8* __restrict__ W2v = (const bf16x8*)W2p;
  const bf16x8* __restrict__ W3v = (const bf16x8*)W3p;

  // ---- stage 1: act1 = swish(basis @ W1 + b1); bias folded into acc init ----
  {
    f32x4 acc[4][4];
#pragma unroll
    for (int c = 0; c < 4; ++c) {
      float bs = b1[wv*64 + c*16 + r];
      f32x4 bv = {bs, bs, bs, bs};
#pragma unroll
      for (int a = 0; a < 4; ++a) acc[a][c] = bv;
    }
#pragma unroll
    for (int ks = 0; ks < 2; ++ks) {
      bf16x8 af[4];
#pragma unroll
      for (int rb = 0; rb < 4; ++rb) {
        int row = m0 + rb*16 + r;
        af[rb] = *reinterpret_cast<const bf16x8*>((const char*)basis + (size_t)row*128 + ks*64 + q*16);
      }
#pragma unroll
      for (int c2 = 0; c2 < 2; ++c2) {
        bf16x8 bfr[2];
#pragma unroll
        for (int j = 0; j < 2; ++j)
          bfr[j] = W1v[(size_t)((ks*32 + wv*4 + c2*2 + j)*64 + lane)];
#pragma unroll
        for (int j = 0; j < 2; ++j)
#pragma unroll
          for (int rb = 0; rb < 4; ++rb)
            acc[rb][c2*2 + j] = __builtin_amdgcn_mfma_f32_16x16x32_bf16(af[rb], bfr[j], acc[rb][c2*2 + j], 0, 0, 0);
      }
    }
#pragma unroll
    for (int nt = 0; nt < 4; ++nt) {
      int col = wv*64 + nt*16 + r;
#pragma unroll
      for (int rb = 0; rb < 4; ++rb)
#pragma unroll
        for (int i = 0; i < 4; ++i) {
          int row = rb*16 + q*4 + i;
          int off = row*1024 + ((col*2) ^ ((row & 7) << 4));
          *(uint16_t*)(&actb[off]) = f2bf_trunc(swishf(acc[rb][nt][i]));
        }
    }
  }
  __syncthreads();

  // ---- stage 2: act2 = swish(act1 @ W2 + b2) ----
  {
    f32x4 acc[4][4];
#pragma unroll
    for (int c = 0; c < 4; ++c) {
      float bs = b2[wv*64 + c*16 + r];
      f32x4 bv = {bs, bs, bs, bs};
#pragma unroll
      for (int a = 0; a < 4; ++a) acc[a][c] = bv;
    }
#pragma unroll 2
    for (int ks = 0; ks < 16; ++ks) {
      bf16x8 af[4];
#pragma unroll
      for (int rb = 0; rb < 4; ++rb) {
        int row = rb*16 + r;
        int off = row*1024 + ((ks*64 + q*16) ^ ((row & 7) << 4));
        af[rb] = *reinterpret_cast<const bf16x8*>(&actb[off]);
      }
#pragma unroll
      for (int c2 = 0; c2 < 2; ++c2) {
        bf16x8 bfr[2];
#pragma unroll
        for (int j = 0; j < 2; ++j)
          bfr[j] = W2v[(size_t)((ks*32 + wv*4 + c2*2 + j)*64 + lane)];
#pragma unroll
        for (int j = 0; j < 2; ++j)
#pragma unroll
          for (int rb = 0; rb < 4; ++rb)
            acc[rb][c2*2 + j] = __builtin_amdgcn_mfma_f32_16x16x32_bf16(af[rb], bfr[j], acc[rb][c2*2 + j], 0, 0, 0);
      }
    }
    __syncthreads();   // all waves done READING act1
#pragma unroll
    for (int nt = 0; nt < 4; ++nt) {
      int col = wv*64 + nt*16 + r;
#pragma unroll
      for (int rb = 0; rb < 4; ++rb)
#pragma unroll
        for (int i = 0; i < 4; ++i) {
          int row = rb*16 + q*4 + i;
          int off = row*1024 + ((col*2) ^ ((row & 7) << 4));
          *(uint16_t*)(&actb[off]) = f2bf_trunc(swishf(acc[rb][nt][i]));
        }
    }
  }
  __syncthreads();

  // ---- stage 3: x3 = swish(act2 @ W3 + b3), col63 := 1; 2 tiles/wave ----
  {
    const int rb3 = wv >> 1, ntp = (wv & 1)*2;
    f32x4 acc[2];
#pragma unroll
    for (int j = 0; j < 2; ++j) {
      float bs = b3[(ntp + j)*16 + r];
      f32x4 bv = {bs, bs, bs, bs};
      acc[j] = bv;
    }
#pragma unroll 2
    for (int ks = 0; ks < 16; ++ks) {
      int row = rb3*16 + r;
      int off = row*1024 + ((ks*64 + q*16) ^ ((row & 7) << 4));
      bf16x8 a = *reinterpret_cast<const bf16x8*>(&actb[off]);
#pragma unroll
      for (int j = 0; j < 2; ++j) {
        bf16x8 bb = W3v[(size_t)((ks*4 + ntp + j)*64 + lane)];
        acc[j] = __builtin_amdgcn_mfma_f32_16x16x32_bf16(a, bb, acc[j], 0, 0, 0);
      }
    }
#pragma unroll
    for (int j = 0; j < 2; ++j) {
      int col = (ntp + j)*16 + r;
#pragma unroll
      for (int i = 0; i < 4; ++i) {
        int row = m0 + rb3*16 + q*4 + i;
        float v = swishf(acc[j][i]);
        if (col == 63) v = 1.f;
        x3[(size_t)row*64 + col] = f2bf_trunc(v);
      }
    }
  }
}

// ---------------- TP layer 1 as scaled GEMM ----------------
__global__ __launch_bounds__(512, 4)
void tp1_gemm(const uint16_t* __restrict__ x3, const char* __restrict__ ws,
              const int* __restrict__ eidx, float* __restrict__ agg)
{
  __shared__ __align__(16) uint16_t Wst[2][4096];
  __shared__ float xjs[64*32];
  __shared__ float mbuf[64*64];
  __shared__ float shls[64*3];
  __shared__ int   rowl[64];
  __shared__ int   coll[64];

  const float* hN  = (const float*)(ws + OFF_HN);
  const float* shl = (const float*)(ws + OFF_SHL);
  const char*  W4n = (const char*)(ws + OFF_W4N1);

  const int tid = threadIdx.x, lane = tid & 63, wv = tid >> 6;
  const int e0l = blockIdx.x * 64;
  const int r_ = lane & 15, q_ = lane >> 4;
  const int rowg = wv >> 1, colg = wv & 1;

  if (tid < 64) { rowl[tid] = eidx[e0l + tid]; coll[tid] = eidx[E_EDGES + e0l + tid]; }
  for (int i = tid; i < 192; i += 512) shls[i] = shl[(size_t)e0l*3 + i];
  __syncthreads();
  for (int i = tid; i < 64*32; i += 512) {
    int e = i >> 5, u = i & 31;
    xjs[i] = hN[(size_t)rowl[e]*32 + u];
  }

  bf16x8 a0, a1;
  {
    int row = e0l + rowg*16 + r_;
    const char* base = (const char*)x3 + (size_t)row*128 + q_*16;
    a0 = *reinterpret_cast<const bf16x8*>(base);
    a1 = *reinterpret_cast<const bf16x8*>(base + 64);
  }

  const char* srcW = W4n + ((size_t)(tid >> 6)*64 + lane)*16;
  auto stageW = [&](int buf, int u) {
    __builtin_amdgcn_global_load_lds((const __attribute__((address_space(1))) void*)(srcW + (size_t)u*8192),
        (__attribute__((address_space(3))) void*)(&Wst[buf][(size_t)tid*8]), 16, 0, 0);
  };

  f32x4 zv = {0.f, 0.f, 0.f, 0.f};
  f32x4 accF[2];
  accF[0] = zv; accF[1] = zv;

  stageW(0, 0);
  __syncthreads();

  const char* wb0 = (const char*)&Wst[0][0] + ((size_t)(colg*2)*64 + lane)*16;
  const char* wb1 = (const char*)&Wst[1][0] + ((size_t)(colg*2)*64 + lane)*16;

  int cur = 0;
#pragma unroll 1
  for (int u = 0; u < 30; ++u) {
    if (u + 1 < 30) stageW(cur ^ 1, u + 1);
    const char* wb = cur ? wb1 : wb0;
    bf16x8 b00 = *reinterpret_cast<const bf16x8*>(wb);
    bf16x8 b01 = *reinterpret_cast<const bf16x8*>(wb + 1024);
    bf16x8 b10 = *reinterpret_cast<const bf16x8*>(wb + 4096);
    bf16x8 b11 = *reinterpret_cast<const bf16x8*>(wb + 5120);
    f32x4 t0 = __builtin_amdgcn_mfma_f32_16x16x32_bf16(a0, b00, zv, 0, 0, 0);
    t0 = __builtin_amdgcn_mfma_f32_16x16x32_bf16(a1, b10, t0, 0, 0, 0);
    f32x4 t1 = __builtin_amdgcn_mfma_f32_16x16x32_bf16(a0, b01, zv, 0, 0, 0);
    t1 = __builtin_amdgcn_mfma_f32_16x16x32_bf16(a1, b11, t1, 0, 0, 0);
#pragma unroll
    for (int i = 0; i < 4; ++i) {
      float xv = xjs[(rowg*16 + q_*4 + i)*32 + u];
      accF[0][i] += xv * t0[i];
      accF[1][i] += xv * t1[i];
    }
    if (u + 1 < 30) {
      asm volatile("s_waitcnt vmcnt(0)" ::: "memory");
      __builtin_amdgcn_s_barrier();
      cur ^= 1;
    }
  }

#pragma unroll
  for (int nt = 0; nt < 2; ++nt)
#pragma unroll
    for (int i = 0; i < 4; ++i)
      mbuf[(rowg*16 + q_*4 + i)*64 + colg*32 + nt*16 + r_] = accF[nt][i];
  __syncthreads();

#pragma unroll 1
  for (int i = tid; i < 64*70; i += 512) {
    int e = i/70, c = i - e*70;
    float v;
    if (c < 40) v = mbuf[e*64 + c] * SH0C;
    else { int vv = (c - 40)/3, k = (c - 40) - vv*3; v = mbuf[e*64 + 40 + vv] * shls[e*3 + k]; }
    atomicAdd(&agg[(size_t)coll[e]*70 + c], v);
  }
}

// ---------------- TP layer 2 ----------------
__global__ __launch_bounds__(512, 2)
void tp2_kernel(const uint16_t* __restrict__ x3, const char* __restrict__ ws,
                const int* __restrict__ eidx, float* __restrict__ agg2)
{
  constexpr int P2 = 67;
  __shared__ float wbuf2[64 * P2];
  __shared__ float xjs[64*30];
  __shared__ float xjv[64*30];
  __shared__ float Db[64*10];
  __shared__ float shls[64*3];
  __shared__ int   rowl[64];
  __shared__ int   coll[64];

  const float* h2  = (const float*)(ws + OFF_H2);
  const float* shl = (const float*)(ws + OFF_SHL);
  const float* b4p = (const float*)(ws + OFF_B4P2);
  const bf16x8* __restrict__ bv4 = (const bf16x8*)(ws + OFF_W4P2);

  const int tid = threadIdx.x, lane = tid & 63, wv = tid >> 6;
  const int e0l = blockIdx.x * 64;
  const int r_ = lane & 15, q_ = lane >> 4;

  if (tid < 64) { rowl[tid] = eidx[e0l + tid]; coll[tid] = eidx[E_EDGES + e0l + tid]; }
  for (int i = tid; i < 192; i += 512) shls[i] = shl[(size_t)e0l*3 + i];
  __syncthreads();
  for (int i = tid; i < 64*60; i += 512) {
    int e = i/60, u = i - e*60;
    float v = h2[(size_t)rowl[e]*64 + u];
    if (u < 30) xjs[e*30 + u] = v; else xjv[e*30 + (u - 30)] = v;
  }
  __syncthreads();
  for (int i = tid; i < 640; i += 512) {
    int e = i/10, v = i - e*10;
    float d = 0.f;
#pragma unroll
    for (int m = 0; m < 3; ++m) d += xjv[e*30 + v*3 + m] * shls[e*3 + m];
    Db[i] = d * INV_SQRT3;
  }

  const int rbase = (wv >> 2)*2, nt4 = wv & 3;
  bf16x8 a4[2][2];
#pragma unroll
  for (int kk = 0; kk < 2; ++kk)
#pragma unroll
    for (int rbi = 0; rbi < 2; ++rbi) {
      int row = e0l + (rbase + rbi)*16 + r_;
      a4[kk][rbi] = *reinterpret_cast<const bf16x8*>((const char*)x3 + (size_t)row*128 + kk*64 + q_*16);
    }
  f32x4 acc[2];
  f32x4 zv = {0.f, 0.f, 0.f, 0.f};
  acc[0] = zv; acc[1] = zv;
#pragma unroll
  for (int kk = 0; kk < 2; ++kk) {
    bf16x8 b4 = bv4[(size_t)(kk*4 + nt4)*64 + lane];
#pragma unroll
    for (int rbi = 0; rbi < 2; ++rbi)
      acc[rbi] = __builtin_amdgcn_mfma_f32_16x16x32_bf16(a4[kk][rbi], b4, acc[rbi], 0, 0, 0);
  }
  __syncthreads();
  {
    int cg = nt4*16 + r_;
    float bs = b4p[cg];
#pragma unroll
    for (int rbi = 0; rbi < 2; ++rbi)
#pragma unroll
      for (int i2 = 0; i2 < 4; ++i2) {
        int e = (rbase + rbi)*16 + q_*4 + i2;
        wbuf2[e*P2 + cg] = acc[rbi][i2] + bs;
      }
  }
  __syncthreads();

  if (tid < 64) {
    int e = tid;
    float m = 0.f, m2 = 0.f;
#pragma unroll
    for (int c = 0; c < 30; ++c) m += xjs[e*30 + c] * wbuf2[e*P2 + c];
#pragma unroll
    for (int vv = 0; vv < 10; ++vv) m2 += Db[e*10 + vv] * wbuf2[e*P2 + 30 + vv];
    atomicAdd(&agg2[coll[e]], m * (SH0C * INV_SQRT30) + m2 * INV_SQRT10);
  }
}

// ---------------- node kernels ----------------
__global__ void node_mid(char* ws, const float* __restrict__ si1w)
{
  int nid = blockIdx.x * blockDim.x + threadIdx.x;
  if (nid >= N_NODES) return;
  const float* hN  = (const float*)(ws + OFF_HN)  + (size_t)nid*32;
  const float* agg = (const float*)(ws + OFF_AGG) + (size_t)nid*70;
  float* h2        = (float*)(ws + OFF_H2)        + (size_t)nid*64;

  float hn[30];
#pragma unroll
  for (int u = 0; u < 30; ++u) hn[u] = hN[u];

  float h1[70];
#pragma unroll 1
  for (int v = 0; v < 40; ++v) {
    float s = 0.f;
#pragma unroll
    for (int u = 0; u < 30; ++u) s += hn[u] * si1w[u*40 + v];
    h1[v] = SQ2C * (s + agg[v]);
  }
#pragma unroll
  for (int c = 40; c < 70; ++c) h1[c] = agg[c];

#pragma unroll
  for (int u = 0; u < 30; ++u) h2[u] = swishf(h1[u]);
#pragma unroll
  for (int v = 0; v < 10; ++v) {
    float g = 1.f / (1.f + __expf(-h1[30 + v]));
#pragma unroll
    for (int k = 0; k < 3; ++k) h2[30 + v*3 + k] = h1[40 + v*3 + k] * g;
  }
}

__global__ void node_final(char* ws, const float* __restrict__ si2w, const int* __restrict__ batch)
{
  __shared__ float ls[NGRAPH];
  if (threadIdx.x < NGRAPH) ls[threadIdx.x] = 0.f;
  __syncthreads();
  int nid = blockIdx.x * blockDim.x + threadIdx.x;
  if (nid < N_NODES) {
    const float* h2   = (const float*)(ws + OFF_H2) + (size_t)nid*64;
    const float* agg2 = (const float*)(ws + OFF_AGG2);
    float s2 = 0.f;
#pragma unroll
    for (int u = 0; u < 30; ++u) s2 += h2[u] * si2w[u];
    float val = SQ2C * (s2 * INV_SQRT30 + agg2[nid]);
    atomicAdd(&ls[batch[nid]], val);
  }
  __syncthreads();
  if (threadIdx.x < NGRAPH)
    atomicAdd(((float*)(ws + OFF_GSUM)) + threadIdx.x, ls[threadIdx.x]);
}

__global__ void write_out(const char* ws, float* out)
{
  int g = threadIdx.x;
  if (g < NGRAPH) out[g] = ((const float*)(ws + OFF_GSUM))[g];
}

// ---------------- launch ----------------
extern "C" void kernel_launch(void* const* d_in, const int* in_sizes, int n_in,
                              void* d_out, int out_size, void* d_ws, size_t ws_size,
                              hipStream_t stream)
{
  const float* pos  = (const float*)d_in[0];
  const float* emb  = (const float*)d_in[1];
  const float* si1w = (const float*)d_in[2];
  const float* si2w = (const float*)d_in[3];
  const float* w1a = (const float*)d_in[4];  const float* b1a = (const float*)d_in[5];
  const float* w2a = (const float*)d_in[6];  const float* b2a = (const float*)d_in[7];
  const float* w3a = (const float*)d_in[8];  const float* b3a = (const float*)d_in[9];
  const float* w4a = (const float*)d_in[10]; const float* b4a = (const float*)d_in[11];
  const float* w1b = (const float*)d_in[12]; const float* b1b = (const float*)d_in[13];
  const float* w2b = (const float*)d_in[14]; const float* b2b = (const float*)d_in[15];
  const float* w3b = (const float*)d_in[16]; const float* b3b = (const float*)d_in[17];
  const float* w4b = (const float*)d_in[18]; const float* b4b = (const float*)d_in[19];
  const int* z     = (const int*)d_in[20];
  const int* eidx  = (const int*)d_in[21];
  const int* batch = (const int*)d_in[22];
  char* ws = (char*)d_ws;

  uint16_t* basis = (uint16_t*)(ws + OFF_BAS);
  float*    shl   = (float*)(ws + OFF_SHL);
  uint16_t* x3    = (uint16_t*)(ws + OFF_X3);

  hipMemsetAsync(ws + OFF_AGG, 0, OFF_ZEND - OFF_AGG, stream);

  prep_kernel<<<1437, 256, 0, stream>>>(w1a, w2a, w3a, w4a, w1b, w2b, w3b, w4b,
                                        b1a, b2a, b3a, b4a, b1b, b2b, b3b, b4b,
                                        emb, z, ws);
  edge_meta<<<E_EDGES/256, 256, 0, stream>>>(pos, eidx, basis, shl);

  // ---- layer 1 ----
  fused_mlp<<<E_EDGES/64, 512, 0, stream>>>(basis,
      (const uint16_t*)(ws + OFF_W1P1), (const float*)(ws + OFF_B1P1),
      (const uint16_t*)(ws + OFF_W2P1), (const float*)(ws + OFF_B2P1),
      (const uint16_t*)(ws + OFF_W3P1), (const float*)(ws + OFF_B3P1), x3);
  tp1_gemm<<<E_EDGES/64, 512, 0, stream>>>(x3, ws, eidx, (float*)(ws + OFF_AGG));

  node_mid<<<N_NODES/256, 256, 0, stream>>>(ws, si1w);

  // ---- layer 2 ----
  fused_mlp<<<E_EDGES/64, 512, 0, stream>>>(basis,
      (const uint16_t*)(ws + OFF_W1P2), (const float*)(ws + OFF_B1P2),
      (const uint16_t*)(ws + OFF_W2P2), (const float*)(ws + OFF_B2P2),
      (const uint16_t*)(ws + OFF_W3P2), (const float*)(ws + OFF_B3P2), x3);
  tp2_kernel<<<E_EDGES/64, 512, 0, stream>>>(x3, ws, eidx, (float*)(ws + OFF_AGG2));

  node_final<<<N_NODES/256, 256, 0, stream>>>(ws, si2w, batch);
  write_out<<<1, 64, 0, stream>>>(ws, (float*)d_out);
}

// Round 22
// 583.574 us; speedup vs baseline: 1.3220x; 1.0637x over previous
//
#include <hip/hip_runtime.h>
#include <stdint.h>

typedef __attribute__((ext_vector_type(8))) short bf16x8;
typedef __attribute__((ext_vector_type(4))) float f32x4;

#define N_NODES 8192
#define E_EDGES 163840
#define NGRAPH  32

#define INV_SQRT30 0.18257419f
#define SH0C       0.22360680f   /* 1/sqrt(20) */
#define SQRT3C     1.73205081f
#define INV_SQRT3  0.57735027f
#define INV_SQRT10 0.31622777f
#define SQ2C       0.70710678f

// ---------------- workspace layout (bytes) ----------------
enum : unsigned {
  OFF_W1P1 = 0u,       OFF_W2P1 = 65536u,   OFF_W3P1 = 589824u,  OFF_W4P1 = 655360u,
  OFF_W1P2 = 851968u,  OFF_W2P2 = 917504u,  OFF_W3P2 = 1441792u, OFF_W4P2 = 1507328u,
  OFF_B1P1 = 1515520u, OFF_B2P1 = 1517568u, OFF_B3P1 = 1519616u, OFF_B4P1 = 1519872u,
  OFF_B1P2 = 1526016u, OFF_B2P2 = 1528064u, OFF_B3P2 = 1530112u, OFF_B4P2 = 1530368u,
  OFF_HN   = 1530624u, // [8192][32] f32
  OFF_H2   = 2579200u, // [8192][64] f32
  OFF_AGG  = 4676352u, // [8192][70] f32
  OFF_AGG2 = 6970112u, // [8192] f32
  OFF_GSUM = 7002880u, // [32] f32
  OFF_ZEND = 7003008u,
  OFF_SHL  = 7003136u,  // [E][3] f32
  OFF_BAS  = 8969216u,  // [E][64] bf16 (linear)
  OFF_W4N1 = 29940736u, // 30 x 8 x 1KB
  OFF_X3   = 30186496u  // [E][64] bf16
};

__device__ __forceinline__ uint16_t f2bf(float f){
  union { float f; uint32_t u; } v; v.f = f;
  uint32_t r = v.u + 0x7fffu + ((v.u >> 16) & 1u);
  return (uint16_t)(r >> 16);
}
__device__ __forceinline__ float swishf(float x){ return x / (1.f + __expf(-x)); }

// ---------------- weight pre-pack (f32 src -> bf16 MFMA B-fragment order) ----------------
__device__ __forceinline__ void pack_mat(const float* __restrict__ src, int K, int N, int NP,
                                         uint16_t* __restrict__ dst, int t)
{
  int lane = t & 63;
  int tile = t >> 6;
  int NT = NP >> 4;
  int nn = tile % NT, kk = tile / NT;
  int k0 = kk*32 + ((lane >> 4) << 3);
  int n  = nn*16 + (lane & 15);
  union { short s[8]; bf16x8 v; } tmp;
#pragma unroll
  for (int b = 0; b < 8; ++b) {
    int k = k0 + b;
    tmp.s[b] = (k < K && n < N) ? (short)f2bf(src[(size_t)k*N + n]) : (short)0;
  }
  *reinterpret_cast<bf16x8*>(dst + (size_t)t*8) = tmp.v;
}

// W4' pack for tp1-as-GEMM
__device__ __forceinline__ void pack_w4n(const float* __restrict__ w4, const float* __restrict__ b4,
                                         uint16_t* __restrict__ dst, int t)
{
  int lane = t & 63;
  int tile = t >> 6;           // 0..239
  int u = tile >> 3, j = tile & 7;
  int kk = j >> 2, nn = j & 3;
  int k0 = kk*32 + ((lane >> 4) << 3);
  int n  = nn*16 + (lane & 15);
  union { short s[8]; bf16x8 v; } tmp;
#pragma unroll
  for (int b = 0; b < 8; ++b) {
    int k = k0 + b;
    float val = 0.f;
    if (n < 50) {
      int cg = (n < 40) ? (u*40 + n) : (1200 + u*10 + (n - 40));
      if (k < 50) val = w4[(size_t)k*1500 + cg];
      else if (k == 63) val = b4[cg];
    }
    tmp.s[b] = (short)f2bf(val);
  }
  *reinterpret_cast<bf16x8*>(dst + (size_t)t*8) = tmp.v;
}

__global__ void prep_kernel(const float* w1a, const float* w2a, const float* w3a, const float* w4a,
                            const float* w1b, const float* w2b, const float* w3b, const float* w4b,
                            const float* b1a, const float* b2a, const float* b3a, const float* b4a,
                            const float* b1b, const float* b2b, const float* b3b, const float* b4b,
                            const float* emb, const int* z, char* ws)
{
  int t = blockIdx.x * 256 + threadIdx.x;
  if      (t < 4096)   pack_mat(w1a, 40, 500, 512,  (uint16_t*)(ws + OFF_W1P1), t);
  else if (t < 36864)  pack_mat(w2a, 500,500, 512,  (uint16_t*)(ws + OFF_W2P1), t - 4096);
  else if (t < 40960)  pack_mat(w3a, 500, 50, 64,   (uint16_t*)(ws + OFF_W3P1), t - 36864);
  else if (t < 45056)  { /* spare */ }
  else if (t < 49152)  pack_mat(w1b, 40, 500, 512,  (uint16_t*)(ws + OFF_W1P2), t - 45056);
  else if (t < 81920)  pack_mat(w2b, 500,500, 512,  (uint16_t*)(ws + OFF_W2P2), t - 49152);
  else if (t < 86016)  pack_mat(w3b, 500, 50, 64,   (uint16_t*)(ws + OFF_W3P2), t - 81920);
  else if (t < 86528)  pack_mat(w4b, 50,  40, 64,   (uint16_t*)(ws + OFF_W4P2), t - 86016);
  else if (t < 90304) {
    int loc = t - 86528;
    const float* src; float* dst; int realN;
    if      (loc < 512)  { src=b1a; dst=(float*)(ws+OFF_B1P1); realN=500; }
    else if (loc < 1024) { src=b2a; dst=(float*)(ws+OFF_B2P1); realN=500;  loc -= 512;  }
    else if (loc < 1088) { src=b3a; dst=(float*)(ws+OFF_B3P1); realN=50;   loc -= 1024; }
    else if (loc < 2624) { src=b4a; dst=(float*)(ws+OFF_B4P1); realN=1500; loc -= 1088; }
    else if (loc < 3136) { src=b1b; dst=(float*)(ws+OFF_B1P2); realN=500;  loc -= 2624; }
    else if (loc < 3648) { src=b2b; dst=(float*)(ws+OFF_B2P2); realN=500;  loc -= 3136; }
    else if (loc < 3712) { src=b3b; dst=(float*)(ws+OFF_B3P2); realN=50;   loc -= 3648; }
    else                 { src=b4b; dst=(float*)(ws+OFF_B4P2); realN=40;   loc -= 3712; }
    dst[loc] = (loc < realN) ? src[loc] : 0.f;
  }
  else if (t < 352448) {
    int i = t - 90304;
    int n = i >> 5, u = i & 31;
    float v = 0.f;
    if (u < 30) v = emb[(size_t)z[n]*30 + u] * INV_SQRT30;
    ((float*)(ws + OFF_HN))[i] = v;
  }
  else if (t < 367808) {
    pack_w4n(w4a, b4a, (uint16_t*)(ws + OFF_W4N1), t - 352448);
  }
}

// ---------------- edge meta ----------------
__global__ void edge_meta(const float* __restrict__ pos, const int* __restrict__ eidx,
                          uint16_t* __restrict__ basis, float* __restrict__ shl)
{
  int e = blockIdx.x * 256 + threadIdx.x;
  if (e >= E_EDGES) return;
  int rn = eidx[e], cn = eidx[E_EDGES + e];
  float ax = pos[rn*3+0] - pos[cn*3+0];
  float ay = pos[rn*3+1] - pos[cn*3+1];
  float az = pos[rn*3+2] - pos[cn*3+2];
  float rr = sqrtf(ax*ax + ay*ay + az*az + 1e-12f);
  float s = SQRT3C * SH0C / rr;
  shl[e*3+0] = ax*s; shl[e*3+1] = ay*s; shl[e*3+2] = az*s;
#pragma unroll
  for (int j = 0; j < 8; ++j) {
    union { short s[8]; bf16x8 v; } tmp;
#pragma unroll
    for (int b = 0; b < 8; ++b) {
      int c = j*8 + b;
      float vv = 0.f;
      if (c < 40) { float t = rr*3.9f - (float)c; vv = __expf(-t*t); }
      tmp.s[b] = (short)f2bf(vv);
    }
    *reinterpret_cast<bf16x8*>(basis + (size_t)e*64 + j*8) = tmp.v;
  }
}

// ---------------- fused MLP, 64-row tiles, (512,2) + B register prefetch ----------------
__global__ __launch_bounds__(512, 2)
void fused_mlp(const uint16_t* __restrict__ basis,
               const uint16_t* __restrict__ W1p, const float* __restrict__ b1,
               const uint16_t* __restrict__ W2p, const float* __restrict__ b2,
               const uint16_t* __restrict__ W3p, const float* __restrict__ b3,
               uint16_t* __restrict__ x3)
{
  __shared__ __align__(16) char actb[65536];   // [64][512] bf16, XOR-swizzled

  const int tid = threadIdx.x, lane = tid & 63, wv = tid >> 6;
  const int m0 = blockIdx.x * 64;
  const int r = lane & 15, q = lane >> 4;

  const bf16x8* __restrict__ W1v = (const bf16x8*)W1p;
  const bf16x8* __restrict__ W2v = (const bf16x8*)W2p;
  const bf16x8* __restrict__ W3v = (const bf16x8*)W3p;

  f32x4 zv = {0.f, 0.f, 0.f, 0.f};

  // ---- stage 1: act1 = swish(basis @ W1 + b1); A direct from global ----
  {
    f32x4 acc[4][4];
#pragma unroll
    for (int a = 0; a < 4; ++a)
#pragma unroll
      for (int c = 0; c < 4; ++c) acc[a][c] = zv;
#pragma unroll
    for (int ks = 0; ks < 2; ++ks) {
      bf16x8 af[4];
#pragma unroll
      for (int rb = 0; rb < 4; ++rb) {
        int row = m0 + rb*16 + r;
        af[rb] = *reinterpret_cast<const bf16x8*>((const char*)basis + (size_t)row*128 + ks*64 + q*16);
      }
      bf16x8 bfr[4];
#pragma unroll
      for (int j = 0; j < 4; ++j)
        bfr[j] = W1v[(size_t)((ks*32 + wv*4 + j)*64 + lane)];
#pragma unroll
      for (int j = 0; j < 4; ++j)
#pragma unroll
        for (int rb = 0; rb < 4; ++rb)
          acc[rb][j] = __builtin_amdgcn_mfma_f32_16x16x32_bf16(af[rb], bfr[j], acc[rb][j], 0, 0, 0);
    }
#pragma unroll
    for (int nt = 0; nt < 4; ++nt) {
      int col = wv*64 + nt*16 + r;
      float bs = b1[col];
#pragma unroll
      for (int rb = 0; rb < 4; ++rb)
#pragma unroll
        for (int i = 0; i < 4; ++i) {
          int row = rb*16 + q*4 + i;
          int off = row*1024 + ((col*2) ^ ((row & 7) << 4));
          *(uint16_t*)(&actb[off]) = f2bf(swishf(acc[rb][nt][i] + bs));
        }
    }
  }
  __syncthreads();

  // ---- stage 2: act2 = swish(act1 @ W2 + b2); B prefetched one k-step ahead ----
  {
    f32x4 acc[4][4];
#pragma unroll
    for (int a = 0; a < 4; ++a)
#pragma unroll
      for (int c = 0; c < 4; ++c) acc[a][c] = zv;

    bf16x8 bnx[4];
#pragma unroll
    for (int j = 0; j < 4; ++j)
      bnx[j] = W2v[(size_t)((wv*4 + j)*64 + lane)];

#pragma unroll 1
    for (int ks = 0; ks < 16; ++ks) {
      bf16x8 bcur[4];
#pragma unroll
      for (int j = 0; j < 4; ++j) bcur[j] = bnx[j];
      if (ks + 1 < 16) {
#pragma unroll
        for (int j = 0; j < 4; ++j)
          bnx[j] = W2v[(size_t)(((ks + 1)*32 + wv*4 + j)*64 + lane)];
      }
      bf16x8 af[4];
#pragma unroll
      for (int rb = 0; rb < 4; ++rb) {
        int row = rb*16 + r;
        int off = row*1024 + ((ks*64 + q*16) ^ ((row & 7) << 4));
        af[rb] = *reinterpret_cast<const bf16x8*>(&actb[off]);
      }
#pragma unroll
      for (int j = 0; j < 4; ++j)
#pragma unroll
        for (int rb = 0; rb < 4; ++rb)
          acc[rb][j] = __builtin_amdgcn_mfma_f32_16x16x32_bf16(af[rb], bcur[j], acc[rb][j], 0, 0, 0);
    }
    __syncthreads();   // all waves done READING act1
#pragma unroll
    for (int nt = 0; nt < 4; ++nt) {
      int col = wv*64 + nt*16 + r;
      float bs = b2[col];
#pragma unroll
      for (int rb = 0; rb < 4; ++rb)
#pragma unroll
        for (int i = 0; i < 4; ++i) {
          int row = rb*16 + q*4 + i;
          int off = row*1024 + ((col*2) ^ ((row & 7) << 4));
          *(uint16_t*)(&actb[off]) = f2bf(swishf(acc[rb][nt][i] + bs));
        }
    }
  }
  __syncthreads();

  // ---- stage 3: x3 = swish(act2 @ W3 + b3), col63 := 1; B prefetched ----
  {
    const int rb3 = wv >> 1, ntp = (wv & 1)*2;
    f32x4 acc[2];
    acc[0] = zv; acc[1] = zv;

    bf16x8 bnx[2];
#pragma unroll
    for (int j = 0; j < 2; ++j)
      bnx[j] = W3v[(size_t)((ntp + j)*64 + lane)];

#pragma unroll 1
    for (int ks = 0; ks < 16; ++ks) {
      bf16x8 bcur[2];
      bcur[0] = bnx[0]; bcur[1] = bnx[1];
      if (ks + 1 < 16) {
#pragma unroll
        for (int j = 0; j < 2; ++j)
          bnx[j] = W3v[(size_t)(((ks + 1)*4 + ntp + j)*64 + lane)];
      }
      int row = rb3*16 + r;
      int off = row*1024 + ((ks*64 + q*16) ^ ((row & 7) << 4));
      bf16x8 a = *reinterpret_cast<const bf16x8*>(&actb[off]);
#pragma unroll
      for (int j = 0; j < 2; ++j)
        acc[j] = __builtin_amdgcn_mfma_f32_16x16x32_bf16(a, bcur[j], acc[j], 0, 0, 0);
    }
#pragma unroll
    for (int j = 0; j < 2; ++j) {
      int col = (ntp + j)*16 + r;
      float bs = b3[col];
#pragma unroll
      for (int i = 0; i < 4; ++i) {
        int row = m0 + rb3*16 + q*4 + i;
        float v = swishf(acc[j][i] + bs);
        if (col == 63) v = 1.f;
        x3[(size_t)row*64 + col] = f2bf(v);
      }
    }
  }
}

// ---------------- TP layer 1 as scaled GEMM ----------------
__global__ __launch_bounds__(512, 4)
void tp1_gemm(const uint16_t* __restrict__ x3, const char* __restrict__ ws,
              const int* __restrict__ eidx, float* __restrict__ agg)
{
  __shared__ __align__(16) uint16_t Wst[2][4096];
  __shared__ float xjs[64*32];
  __shared__ float mbuf[64*64];
  __shared__ float shls[64*3];
  __shared__ int   rowl[64];
  __shared__ int   coll[64];

  const float* hN  = (const float*)(ws + OFF_HN);
  const float* shl = (const float*)(ws + OFF_SHL);
  const char*  W4n = (const char*)(ws + OFF_W4N1);

  const int tid = threadIdx.x, lane = tid & 63, wv = tid >> 6;
  const int e0l = blockIdx.x * 64;
  const int r_ = lane & 15, q_ = lane >> 4;
  const int rowg = wv >> 1, colg = wv & 1;

  if (tid < 64) { rowl[tid] = eidx[e0l + tid]; coll[tid] = eidx[E_EDGES + e0l + tid]; }
  for (int i = tid; i < 192; i += 512) shls[i] = shl[(size_t)e0l*3 + i];
  __syncthreads();
  for (int i = tid; i < 64*32; i += 512) {
    int e = i >> 5, u = i & 31;
    xjs[i] = hN[(size_t)rowl[e]*32 + u];
  }

  bf16x8 a0, a1;
  {
    int row = e0l + rowg*16 + r_;
    const char* base = (const char*)x3 + (size_t)row*128 + q_*16;
    a0 = *reinterpret_cast<const bf16x8*>(base);
    a1 = *reinterpret_cast<const bf16x8*>(base + 64);
  }

  const char* srcW = W4n + ((size_t)(tid >> 6)*64 + lane)*16;
  auto stageW = [&](int buf, int u) {
    __builtin_amdgcn_global_load_lds((const __attribute__((address_space(1))) void*)(srcW + (size_t)u*8192),
        (__attribute__((address_space(3))) void*)(&Wst[buf][(size_t)tid*8]), 16, 0, 0);
  };

  f32x4 zv = {0.f, 0.f, 0.f, 0.f};
  f32x4 accF[2];
  accF[0] = zv; accF[1] = zv;

  stageW(0, 0);
  __syncthreads();

  const char* wb0 = (const char*)&Wst[0][0] + ((size_t)(colg*2)*64 + lane)*16;
  const char* wb1 = (const char*)&Wst[1][0] + ((size_t)(colg*2)*64 + lane)*16;

  int cur = 0;
#pragma unroll 1
  for (int u = 0; u < 30; ++u) {
    if (u + 1 < 30) stageW(cur ^ 1, u + 1);
    const char* wb = cur ? wb1 : wb0;
    bf16x8 b00 = *reinterpret_cast<const bf16x8*>(wb);
    bf16x8 b01 = *reinterpret_cast<const bf16x8*>(wb + 1024);
    bf16x8 b10 = *reinterpret_cast<const bf16x8*>(wb + 4096);
    bf16x8 b11 = *reinterpret_cast<const bf16x8*>(wb + 5120);
    f32x4 t0 = __builtin_amdgcn_mfma_f32_16x16x32_bf16(a0, b00, zv, 0, 0, 0);
    t0 = __builtin_amdgcn_mfma_f32_16x16x32_bf16(a1, b10, t0, 0, 0, 0);
    f32x4 t1 = __builtin_amdgcn_mfma_f32_16x16x32_bf16(a0, b01, zv, 0, 0, 0);
    t1 = __builtin_amdgcn_mfma_f32_16x16x32_bf16(a1, b11, t1, 0, 0, 0);
#pragma unroll
    for (int i = 0; i < 4; ++i) {
      float xv = xjs[(rowg*16 + q_*4 + i)*32 + u];
      accF[0][i] += xv * t0[i];
      accF[1][i] += xv * t1[i];
    }
    if (u + 1 < 30) {
      asm volatile("s_waitcnt vmcnt(0)" ::: "memory");
      __builtin_amdgcn_s_barrier();
      cur ^= 1;
    }
  }

#pragma unroll
  for (int nt = 0; nt < 2; ++nt)
#pragma unroll
    for (int i = 0; i < 4; ++i)
      mbuf[(rowg*16 + q_*4 + i)*64 + colg*32 + nt*16 + r_] = accF[nt][i];
  __syncthreads();

#pragma unroll 1
  for (int i = tid; i < 64*70; i += 512) {
    int e = i/70, c = i - e*70;
    float v;
    if (c < 40) v = mbuf[e*64 + c] * SH0C;
    else { int vv = (c - 40)/3, k = (c - 40) - vv*3; v = mbuf[e*64 + 40 + vv] * shls[e*3 + k]; }
    atomicAdd(&agg[(size_t)coll[e]*70 + c], v);
  }
}

// ---------------- TP layer 2 ----------------
__global__ __launch_bounds__(512, 2)
void tp2_kernel(const uint16_t* __restrict__ x3, const char* __restrict__ ws,
                const int* __restrict__ eidx, float* __restrict__ agg2)
{
  constexpr int P2 = 67;
  __shared__ float wbuf2[64 * P2];
  __shared__ float xjs[64*30];
  __shared__ float xjv[64*30];
  __shared__ float Db[64*10];
  __shared__ float shls[64*3];
  __shared__ int   rowl[64];
  __shared__ int   coll[64];

  const float* h2  = (const float*)(ws + OFF_H2);
  const float* shl = (const float*)(ws + OFF_SHL);
  const float* b4p = (const float*)(ws + OFF_B4P2);
  const bf16x8* __restrict__ bv4 = (const bf16x8*)(ws + OFF_W4P2);

  const int tid = threadIdx.x, lane = tid & 63, wv = tid >> 6;
  const int e0l = blockIdx.x * 64;
  const int r_ = lane & 15, q_ = lane >> 4;

  if (tid < 64) { rowl[tid] = eidx[e0l + tid]; coll[tid] = eidx[E_EDGES + e0l + tid]; }
  for (int i = tid; i < 192; i += 512) shls[i] = shl[(size_t)e0l*3 + i];
  __syncthreads();
  for (int i = tid; i < 64*60; i += 512) {
    int e = i/60, u = i - e*60;
    float v = h2[(size_t)rowl[e]*64 + u];
    if (u < 30) xjs[e*30 + u] = v; else xjv[e*30 + (u - 30)] = v;
  }
  __syncthreads();
  for (int i = tid; i < 640; i += 512) {
    int e = i/10, v = i - e*10;
    float d = 0.f;
#pragma unroll
    for (int m = 0; m < 3; ++m) d += xjv[e*30 + v*3 + m] * shls[e*3 + m];
    Db[i] = d * INV_SQRT3;
  }

  const int rbase = (wv >> 2)*2, nt4 = wv & 3;
  bf16x8 a4[2][2];
#pragma unroll
  for (int kk = 0; kk < 2; ++kk)
#pragma unroll
    for (int rbi = 0; rbi < 2; ++rbi) {
      int row = e0l + (rbase + rbi)*16 + r_;
      a4[kk][rbi] = *reinterpret_cast<const bf16x8*>((const char*)x3 + (size_t)row*128 + kk*64 + q_*16);
    }
  f32x4 acc[2];
  f32x4 zv = {0.f, 0.f, 0.f, 0.f};
  acc[0] = zv; acc[1] = zv;
#pragma unroll
  for (int kk = 0; kk < 2; ++kk) {
    bf16x8 b4 = bv4[(size_t)(kk*4 + nt4)*64 + lane];
#pragma unroll
    for (int rbi = 0; rbi < 2; ++rbi)
      acc[rbi] = __builtin_amdgcn_mfma_f32_16x16x32_bf16(a4[kk][rbi], b4, acc[rbi], 0, 0, 0);
  }
  __syncthreads();
  {
    int cg = nt4*16 + r_;
    float bs = b4p[cg];
#pragma unroll
    for (int rbi = 0; rbi < 2; ++rbi)
#pragma unroll
      for (int i2 = 0; i2 < 4; ++i2) {
        int e = (rbase + rbi)*16 + q_*4 + i2;
        wbuf2[e*P2 + cg] = acc[rbi][i2] + bs;
      }
  }
  __syncthreads();

  if (tid < 64) {
    int e = tid;
    float m = 0.f, m2 = 0.f;
#pragma unroll
    for (int c = 0; c < 30; ++c) m += xjs[e*30 + c] * wbuf2[e*P2 + c];
#pragma unroll
    for (int vv = 0; vv < 10; ++vv) m2 += Db[e*10 + vv] * wbuf2[e*P2 + 30 + vv];
    atomicAdd(&agg2[coll[e]], m * (SH0C * INV_SQRT30) + m2 * INV_SQRT10);
  }
}

// ---------------- node kernels ----------------
__global__ void node_mid(char* ws, const float* __restrict__ si1w)
{
  int nid = blockIdx.x * blockDim.x + threadIdx.x;
  if (nid >= N_NODES) return;
  const float* hN  = (const float*)(ws + OFF_HN)  + (size_t)nid*32;
  const float* agg = (const float*)(ws + OFF_AGG) + (size_t)nid*70;
  float* h2        = (float*)(ws + OFF_H2)        + (size_t)nid*64;

  float hn[30];
#pragma unroll
  for (int u = 0; u < 30; ++u) hn[u] = hN[u];

  float h1[70];
#pragma unroll 1
  for (int v = 0; v < 40; ++v) {
    float s = 0.f;
#pragma unroll
    for (int u = 0; u < 30; ++u) s += hn[u] * si1w[u*40 + v];
    h1[v] = SQ2C * (s + agg[v]);
  }
#pragma unroll
  for (int c = 40; c < 70; ++c) h1[c] = agg[c];

#pragma unroll
  for (int u = 0; u < 30; ++u) h2[u] = swishf(h1[u]);
#pragma unroll
  for (int v = 0; v < 10; ++v) {
    float g = 1.f / (1.f + __expf(-h1[30 + v]));
#pragma unroll
    for (int k = 0; k < 3; ++k) h2[30 + v*3 + k] = h1[40 + v*3 + k] * g;
  }
}

__global__ void node_final(char* ws, const float* __restrict__ si2w, const int* __restrict__ batch)
{
  __shared__ float ls[NGRAPH];
  if (threadIdx.x < NGRAPH) ls[threadIdx.x] = 0.f;
  __syncthreads();
  int nid = blockIdx.x * blockDim.x + threadIdx.x;
  if (nid < N_NODES) {
    const float* h2   = (const float*)(ws + OFF_H2) + (size_t)nid*64;
    const float* agg2 = (const float*)(ws + OFF_AGG2);
    float s2 = 0.f;
#pragma unroll
    for (int u = 0; u < 30; ++u) s2 += h2[u] * si2w[u];
    float val = SQ2C * (s2 * INV_SQRT30 + agg2[nid]);
    atomicAdd(&ls[batch[nid]], val);
  }
  __syncthreads();
  if (threadIdx.x < NGRAPH)
    atomicAdd(((float*)(ws + OFF_GSUM)) + threadIdx.x, ls[threadIdx.x]);
}

__global__ void write_out(const char* ws, float* out)
{
  int g = threadIdx.x;
  if (g < NGRAPH) out[g] = ((const float*)(ws + OFF_GSUM))[g];
}

// ---------------- launch ----------------
extern "C" void kernel_launch(void* const* d_in, const int* in_sizes, int n_in,
                              void* d_out, int out_size, void* d_ws, size_t ws_size,
                              hipStream_t stream)
{
  const float* pos  = (const float*)d_in[0];
  const float* emb  = (const float*)d_in[1];
  const float* si1w = (const float*)d_in[2];
  const float* si2w = (const float*)d_in[3];
  const float* w1a = (const float*)d_in[4];  const float* b1a = (const float*)d_in[5];
  const float* w2a = (const float*)d_in[6];  const float* b2a = (const float*)d_in[7];
  const float* w3a = (const float*)d_in[8];  const float* b3a = (const float*)d_in[9];
  const float* w4a = (const float*)d_in[10]; const float* b4a = (const float*)d_in[11];
  const float* w1b = (const float*)d_in[12]; const float* b1b = (const float*)d_in[13];
  const float* w2b = (const float*)d_in[14]; const float* b2b = (const float*)d_in[15];
  const float* w3b = (const float*)d_in[16]; const float* b3b = (const float*)d_in[17];
  const float* w4b = (const float*)d_in[18]; const float* b4b = (const float*)d_in[19];
  const int* z     = (const int*)d_in[20];
  const int* eidx  = (const int*)d_in[21];
  const int* batch = (const int*)d_in[22];
  char* ws = (char*)d_ws;

  uint16_t* basis = (uint16_t*)(ws + OFF_BAS);
  float*    shl   = (float*)(ws + OFF_SHL);
  uint16_t* x3    = (uint16_t*)(ws + OFF_X3);

  hipMemsetAsync(ws + OFF_AGG, 0, OFF_ZEND - OFF_AGG, stream);

  prep_kernel<<<1437, 256, 0, stream>>>(w1a, w2a, w3a, w4a, w1b, w2b, w3b, w4b,
                                        b1a, b2a, b3a, b4a, b1b, b2b, b3b, b4b,
                                        emb, z, ws);
  edge_meta<<<E_EDGES/256, 256, 0, stream>>>(pos, eidx, basis, shl);

  // ---- layer 1 ----
  fused_mlp<<<E_EDGES/64, 512, 0, stream>>>(basis,
      (const uint16_t*)(ws + OFF_W1P1), (const float*)(ws + OFF_B1P1),
      (const uint16_t*)(ws + OFF_W2P1), (const float*)(ws + OFF_B2P1),
      (const uint16_t*)(ws + OFF_W3P1), (const float*)(ws + OFF_B3P1), x3);
  tp1_gemm<<<E_EDGES/64, 512, 0, stream>>>(x3, ws, eidx, (float*)(ws + OFF_AGG));

  node_mid<<<N_NODES/256, 256, 0, stream>>>(ws, si1w);

  // ---- layer 2 ----
  fused_mlp<<<E_EDGES/64, 512, 0, stream>>>(basis,
      (const uint16_t*)(ws + OFF_W1P2), (const float*)(ws + OFF_B1P2),
      (const uint16_t*)(ws + OFF_W2P2), (const float*)(ws + OFF_B2P2),
      (const uint16_t*)(ws + OFF_W3P2), (const float*)(ws + OFF_B3P2), x3);
  tp2_kernel<<<E_EDGES/64, 512, 0, stream>>>(x3, ws, eidx, (float*)(ws + OFF_AGG2));

  node_final<<<N_NODES/256, 256, 0, stream>>>(ws, si2w, batch);
  write_out<<<1, 64, 0, stream>>>(ws, (float*)d_out);
}

// Round 23
// 532.870 us; speedup vs baseline: 1.4478x; 1.0952x over previous
//
#include <hip/hip_runtime.h>
#include <stdint.h>

typedef __attribute__((ext_vector_type(8))) short bf16x8;
typedef __attribute__((ext_vector_type(4))) float f32x4;

#define N_NODES 8192
#define E_EDGES 163840
#define NGRAPH  32

#define INV_SQRT30 0.18257419f
#define SH0C       0.22360680f   /* 1/sqrt(20) */
#define SQRT3C     1.73205081f
#define INV_SQRT3  0.57735027f
#define INV_SQRT10 0.31622777f
#define SQ2C       0.70710678f

// ---------------- workspace layout (bytes) ----------------
enum : unsigned {
  OFF_W1P1 = 0u,       OFF_W2P1 = 65536u,   OFF_W3P1 = 589824u,  OFF_W4P1 = 655360u,
  OFF_W1P2 = 851968u,  OFF_W2P2 = 917504u,  OFF_W3P2 = 1441792u, OFF_W4P2 = 1507328u,
  OFF_B1P1 = 1515520u, OFF_B2P1 = 1517568u, OFF_B3P1 = 1519616u, OFF_B4P1 = 1519872u,
  OFF_B1P2 = 1526016u, OFF_B2P2 = 1528064u, OFF_B3P2 = 1530112u, OFF_B4P2 = 1530368u,
  OFF_HN   = 1530624u, // [8192][32] f32
  OFF_H2   = 2579200u, // [8192][64] f32
  OFF_AGG  = 4676352u, // [8192][70] f32
  OFF_AGG2 = 6970112u, // [8192] f32
  OFF_GSUM = 7002880u, // [32] f32
  OFF_ZEND = 7003008u,
  OFF_SHL  = 7003136u,  // [E][3] f32
  OFF_BAS  = 8969216u,  // [E][64] bf16 (linear)
  OFF_W4N1 = 29940736u, // 30 x 8 x 1KB
  OFF_X3   = 30186496u  // [E][64] bf16
};

__device__ __forceinline__ uint16_t f2bf(float f){
  union { float f; uint32_t u; } v; v.f = f;
  uint32_t r = v.u + 0x7fffu + ((v.u >> 16) & 1u);
  return (uint16_t)(r >> 16);
}
__device__ __forceinline__ float swishf(float x){ return x / (1.f + __expf(-x)); }
__device__ __forceinline__ float swish_fast(float x){
  float d = 1.f + __expf(-x);
  return x * __builtin_amdgcn_rcpf(d);
}

// ---------------- weight pre-pack (f32 src -> bf16 MFMA B-fragment order) ----------------
__device__ __forceinline__ void pack_mat(const float* __restrict__ src, int K, int N, int NP,
                                         uint16_t* __restrict__ dst, int t)
{
  int lane = t & 63;
  int tile = t >> 6;
  int NT = NP >> 4;
  int nn = tile % NT, kk = tile / NT;
  int k0 = kk*32 + ((lane >> 4) << 3);
  int n  = nn*16 + (lane & 15);
  union { short s[8]; bf16x8 v; } tmp;
#pragma unroll
  for (int b = 0; b < 8; ++b) {
    int k = k0 + b;
    tmp.s[b] = (k < K && n < N) ? (short)f2bf(src[(size_t)k*N + n]) : (short)0;
  }
  *reinterpret_cast<bf16x8*>(dst + (size_t)t*8) = tmp.v;
}

// W4' pack for tp1-as-GEMM
__device__ __forceinline__ void pack_w4n(const float* __restrict__ w4, const float* __restrict__ b4,
                                         uint16_t* __restrict__ dst, int t)
{
  int lane = t & 63;
  int tile = t >> 6;           // 0..239
  int u = tile >> 3, j = tile & 7;
  int kk = j >> 2, nn = j & 3;
  int k0 = kk*32 + ((lane >> 4) << 3);
  int n  = nn*16 + (lane & 15);
  union { short s[8]; bf16x8 v; } tmp;
#pragma unroll
  for (int b = 0; b < 8; ++b) {
    int k = k0 + b;
    float val = 0.f;
    if (n < 50) {
      int cg = (n < 40) ? (u*40 + n) : (1200 + u*10 + (n - 40));
      if (k < 50) val = w4[(size_t)k*1500 + cg];
      else if (k == 63) val = b4[cg];
    }
    tmp.s[b] = (short)f2bf(val);
  }
  *reinterpret_cast<bf16x8*>(dst + (size_t)t*8) = tmp.v;
}

__global__ void prep_kernel(const float* w1a, const float* w2a, const float* w3a, const float* w4a,
                            const float* w1b, const float* w2b, const float* w3b, const float* w4b,
                            const float* b1a, const float* b2a, const float* b3a, const float* b4a,
                            const float* b1b, const float* b2b, const float* b3b, const float* b4b,
                            const float* emb, const int* z, char* ws)
{
  int t = blockIdx.x * 256 + threadIdx.x;
  if      (t < 4096)   pack_mat(w1a, 40, 500, 512,  (uint16_t*)(ws + OFF_W1P1), t);
  else if (t < 36864)  pack_mat(w2a, 500,500, 512,  (uint16_t*)(ws + OFF_W2P1), t - 4096);
  else if (t < 40960)  pack_mat(w3a, 500, 50, 64,   (uint16_t*)(ws + OFF_W3P1), t - 36864);
  else if (t < 45056)  { /* spare */ }
  else if (t < 49152)  pack_mat(w1b, 40, 500, 512,  (uint16_t*)(ws + OFF_W1P2), t - 45056);
  else if (t < 81920)  pack_mat(w2b, 500,500, 512,  (uint16_t*)(ws + OFF_W2P2), t - 49152);
  else if (t < 86016)  pack_mat(w3b, 500, 50, 64,   (uint16_t*)(ws + OFF_W3P2), t - 81920);
  else if (t < 86528)  pack_mat(w4b, 50,  40, 64,   (uint16_t*)(ws + OFF_W4P2), t - 86016);
  else if (t < 90304) {
    int loc = t - 86528;
    const float* src; float* dst; int realN;
    if      (loc < 512)  { src=b1a; dst=(float*)(ws+OFF_B1P1); realN=500; }
    else if (loc < 1024) { src=b2a; dst=(float*)(ws+OFF_B2P1); realN=500;  loc -= 512;  }
    else if (loc < 1088) { src=b3a; dst=(float*)(ws+OFF_B3P1); realN=50;   loc -= 1024; }
    else if (loc < 2624) { src=b4a; dst=(float*)(ws+OFF_B4P1); realN=1500; loc -= 1088; }
    else if (loc < 3136) { src=b1b; dst=(float*)(ws+OFF_B1P2); realN=500;  loc -= 2624; }
    else if (loc < 3648) { src=b2b; dst=(float*)(ws+OFF_B2P2); realN=500;  loc -= 3136; }
    else if (loc < 3712) { src=b3b; dst=(float*)(ws+OFF_B3P2); realN=50;   loc -= 3648; }
    else                 { src=b4b; dst=(float*)(ws+OFF_B4P2); realN=40;   loc -= 3712; }
    dst[loc] = (loc < realN) ? src[loc] : 0.f;
  }
  else if (t < 352448) {
    int i = t - 90304;
    int n = i >> 5, u = i & 31;
    float v = 0.f;
    if (u < 30) v = emb[(size_t)z[n]*30 + u] * INV_SQRT30;
    ((float*)(ws + OFF_HN))[i] = v;
  }
  else if (t < 367808) {
    pack_w4n(w4a, b4a, (uint16_t*)(ws + OFF_W4N1), t - 352448);
  }
}

// ---------------- edge meta ----------------
__global__ void edge_meta(const float* __restrict__ pos, const int* __restrict__ eidx,
                          uint16_t* __restrict__ basis, float* __restrict__ shl)
{
  int e = blockIdx.x * 256 + threadIdx.x;
  if (e >= E_EDGES) return;
  int rn = eidx[e], cn = eidx[E_EDGES + e];
  float ax = pos[rn*3+0] - pos[cn*3+0];
  float ay = pos[rn*3+1] - pos[cn*3+1];
  float az = pos[rn*3+2] - pos[cn*3+2];
  float rr = sqrtf(ax*ax + ay*ay + az*az + 1e-12f);
  float s = SQRT3C * SH0C / rr;
  shl[e*3+0] = ax*s; shl[e*3+1] = ay*s; shl[e*3+2] = az*s;
#pragma unroll
  for (int j = 0; j < 8; ++j) {
    union { short s[8]; bf16x8 v; } tmp;
#pragma unroll
    for (int b = 0; b < 8; ++b) {
      int c = j*8 + b;
      float vv = 0.f;
      if (c < 40) { float t = rr*3.9f - (float)c; vv = __expf(-t*t); }
      tmp.s[b] = (short)f2bf(vv);
    }
    *reinterpret_cast<bf16x8*>(basis + (size_t)e*64 + j*8) = tmp.v;
  }
}

// ---------------- fused MLP, 64-row tiles, (512,2) + B prefetch + lean epilogues ----------------
__global__ __launch_bounds__(512, 2)
void fused_mlp(const uint16_t* __restrict__ basis,
               const uint16_t* __restrict__ W1p, const float* __restrict__ b1,
               const uint16_t* __restrict__ W2p, const float* __restrict__ b2,
               const uint16_t* __restrict__ W3p, const float* __restrict__ b3,
               uint16_t* __restrict__ x3)
{
  __shared__ __align__(16) char actb[65536];   // [64][512] bf16, XOR-swizzled

  const int tid = threadIdx.x, lane = tid & 63, wv = tid >> 6;
  const int m0 = blockIdx.x * 64;
  const int r = lane & 15, q = lane >> 4;

  const bf16x8* __restrict__ W1v = (const bf16x8*)W1p;
  const bf16x8* __restrict__ W2v = (const bf16x8*)W2p;
  const bf16x8* __restrict__ W3v = (const bf16x8*)W3p;

  f32x4 zv = {0.f, 0.f, 0.f, 0.f};
  const int colb2 = (wv*64 + r)*2;   // epilogue column byte base (nt adds 32)

  // ---- stage 1: act1 = swish(basis @ W1 + b1); A direct from global ----
  {
    f32x4 acc[4][4];
#pragma unroll
    for (int a = 0; a < 4; ++a)
#pragma unroll
      for (int c = 0; c < 4; ++c) acc[a][c] = zv;
#pragma unroll
    for (int ks = 0; ks < 2; ++ks) {
      bf16x8 af[4];
#pragma unroll
      for (int rb = 0; rb < 4; ++rb) {
        int row = m0 + rb*16 + r;
        af[rb] = *reinterpret_cast<const bf16x8*>((const char*)basis + (size_t)row*128 + ks*64 + q*16);
      }
      bf16x8 bfr[4];
#pragma unroll
      for (int j = 0; j < 4; ++j)
        bfr[j] = W1v[(size_t)((ks*32 + wv*4 + j)*64 + lane)];
#pragma unroll
      for (int j = 0; j < 4; ++j)
#pragma unroll
        for (int rb = 0; rb < 4; ++rb)
          acc[rb][j] = __builtin_amdgcn_mfma_f32_16x16x32_bf16(af[rb], bfr[j], acc[rb][j], 0, 0, 0);
    }
    float bsv[4];
#pragma unroll
    for (int nt = 0; nt < 4; ++nt) bsv[nt] = b1[wv*64 + nt*16 + r];
#pragma unroll
    for (int rb = 0; rb < 4; ++rb)
#pragma unroll
      for (int i = 0; i < 4; ++i) {
        int row = rb*16 + q*4 + i;
        int rowbase = row*1024;
        int mask = (row & 7) << 4;
#pragma unroll
        for (int nt = 0; nt < 4; ++nt)
          *(uint16_t*)(&actb[rowbase + ((colb2 + nt*32) ^ mask)]) = f2bf(swish_fast(acc[rb][nt][i] + bsv[nt]));
      }
  }
  __syncthreads();

  // ---- stage 2: act2 = swish(act1 @ W2 + b2); B prefetched one k-step ahead ----
  {
    f32x4 acc[4][4];
#pragma unroll
    for (int a = 0; a < 4; ++a)
#pragma unroll
      for (int c = 0; c < 4; ++c) acc[a][c] = zv;

    bf16x8 bnx[4];
#pragma unroll
    for (int j = 0; j < 4; ++j)
      bnx[j] = W2v[(size_t)((wv*4 + j)*64 + lane)];

#pragma unroll 1
    for (int ks = 0; ks < 16; ++ks) {
      bf16x8 bcur[4];
#pragma unroll
      for (int j = 0; j < 4; ++j) bcur[j] = bnx[j];
      if (ks + 1 < 16) {
#pragma unroll
        for (int j = 0; j < 4; ++j)
          bnx[j] = W2v[(size_t)(((ks + 1)*32 + wv*4 + j)*64 + lane)];
      }
      bf16x8 af[4];
#pragma unroll
      for (int rb = 0; rb < 4; ++rb) {
        int row = rb*16 + r;
        int off = row*1024 + ((ks*64 + q*16) ^ ((row & 7) << 4));
        af[rb] = *reinterpret_cast<const bf16x8*>(&actb[off]);
      }
#pragma unroll
      for (int j = 0; j < 4; ++j)
#pragma unroll
        for (int rb = 0; rb < 4; ++rb)
          acc[rb][j] = __builtin_amdgcn_mfma_f32_16x16x32_bf16(af[rb], bcur[j], acc[rb][j], 0, 0, 0);
    }
    __syncthreads();   // all waves done READING act1
    float bsv[4];
#pragma unroll
    for (int nt = 0; nt < 4; ++nt) bsv[nt] = b2[wv*64 + nt*16 + r];
#pragma unroll
    for (int rb = 0; rb < 4; ++rb)
#pragma unroll
      for (int i = 0; i < 4; ++i) {
        int row = rb*16 + q*4 + i;
        int rowbase = row*1024;
        int mask = (row & 7) << 4;
#pragma unroll
        for (int nt = 0; nt < 4; ++nt)
          *(uint16_t*)(&actb[rowbase + ((colb2 + nt*32) ^ mask)]) = f2bf(swish_fast(acc[rb][nt][i] + bsv[nt]));
      }
  }
  __syncthreads();

  // ---- stage 3: x3 = swish(act2 @ W3 + b3), col63 := 1; B prefetched ----
  {
    const int rb3 = wv >> 1, ntp = (wv & 1)*2;
    f32x4 acc[2];
    acc[0] = zv; acc[1] = zv;

    bf16x8 bnx[2];
#pragma unroll
    for (int j = 0; j < 2; ++j)
      bnx[j] = W3v[(size_t)((ntp + j)*64 + lane)];

#pragma unroll 1
    for (int ks = 0; ks < 16; ++ks) {
      bf16x8 bcur[2];
      bcur[0] = bnx[0]; bcur[1] = bnx[1];
      if (ks + 1 < 16) {
#pragma unroll
        for (int j = 0; j < 2; ++j)
          bnx[j] = W3v[(size_t)(((ks + 1)*4 + ntp + j)*64 + lane)];
      }
      int row = rb3*16 + r;
      int off = row*1024 + ((ks*64 + q*16) ^ ((row & 7) << 4));
      bf16x8 a = *reinterpret_cast<const bf16x8*>(&actb[off]);
#pragma unroll
      for (int j = 0; j < 2; ++j)
        acc[j] = __builtin_amdgcn_mfma_f32_16x16x32_bf16(a, bcur[j], acc[j], 0, 0, 0);
    }
#pragma unroll
    for (int j = 0; j < 2; ++j) {
      int col = (ntp + j)*16 + r;
      float bs = b3[col];
#pragma unroll
      for (int i = 0; i < 4; ++i) {
        int row = m0 + rb3*16 + q*4 + i;
        float v = swish_fast(acc[j][i] + bs);
        if (col == 63) v = 1.f;
        x3[(size_t)row*64 + col] = f2bf(v);
      }
    }
  }
}

// ---------------- TP layer 1 as scaled GEMM ----------------
__global__ __launch_bounds__(512, 4)
void tp1_gemm(const uint16_t* __restrict__ x3, const char* __restrict__ ws,
              const int* __restrict__ eidx, float* __restrict__ agg)
{
  __shared__ __align__(16) uint16_t Wst[2][4096];
  __shared__ float xjs[64*32];
  __shared__ float mbuf[64*64];
  __shared__ float shls[64*3];
  __shared__ int   rowl[64];
  __shared__ int   coll[64];

  const float* hN  = (const float*)(ws + OFF_HN);
  const float* shl = (const float*)(ws + OFF_SHL);
  const char*  W4n = (const char*)(ws + OFF_W4N1);

  const int tid = threadIdx.x, lane = tid & 63, wv = tid >> 6;
  const int e0l = blockIdx.x * 64;
  const int r_ = lane & 15, q_ = lane >> 4;
  const int rowg = wv >> 1, colg = wv & 1;

  if (tid < 64) { rowl[tid] = eidx[e0l + tid]; coll[tid] = eidx[E_EDGES + e0l + tid]; }
  for (int i = tid; i < 192; i += 512) shls[i] = shl[(size_t)e0l*3 + i];
  __syncthreads();
  for (int i = tid; i < 64*32; i += 512) {
    int e = i >> 5, u = i & 31;
    xjs[i] = hN[(size_t)rowl[e]*32 + u];
  }

  bf16x8 a0, a1;
  {
    int row = e0l + rowg*16 + r_;
    const char* base = (const char*)x3 + (size_t)row*128 + q_*16;
    a0 = *reinterpret_cast<const bf16x8*>(base);
    a1 = *reinterpret_cast<const bf16x8*>(base + 64);
  }

  const char* srcW = W4n + ((size_t)(tid >> 6)*64 + lane)*16;
  auto stageW = [&](int buf, int u) {
    __builtin_amdgcn_global_load_lds((const __attribute__((address_space(1))) void*)(srcW + (size_t)u*8192),
        (__attribute__((address_space(3))) void*)(&Wst[buf][(size_t)tid*8]), 16, 0, 0);
  };

  f32x4 zv = {0.f, 0.f, 0.f, 0.f};
  f32x4 accF[2];
  accF[0] = zv; accF[1] = zv;

  stageW(0, 0);
  __syncthreads();

  const char* wb0 = (const char*)&Wst[0][0] + ((size_t)(colg*2)*64 + lane)*16;
  const char* wb1 = (const char*)&Wst[1][0] + ((size_t)(colg*2)*64 + lane)*16;

  int cur = 0;
#pragma unroll 1
  for (int u = 0; u < 30; ++u) {
    if (u + 1 < 30) stageW(cur ^ 1, u + 1);
    const char* wb = cur ? wb1 : wb0;
    bf16x8 b00 = *reinterpret_cast<const bf16x8*>(wb);
    bf16x8 b01 = *reinterpret_cast<const bf16x8*>(wb + 1024);
    bf16x8 b10 = *reinterpret_cast<const bf16x8*>(wb + 4096);
    bf16x8 b11 = *reinterpret_cast<const bf16x8*>(wb + 5120);
    f32x4 t0 = __builtin_amdgcn_mfma_f32_16x16x32_bf16(a0, b00, zv, 0, 0, 0);
    t0 = __builtin_amdgcn_mfma_f32_16x16x32_bf16(a1, b10, t0, 0, 0, 0);
    f32x4 t1 = __builtin_amdgcn_mfma_f32_16x16x32_bf16(a0, b01, zv, 0, 0, 0);
    t1 = __builtin_amdgcn_mfma_f32_16x16x32_bf16(a1, b11, t1, 0, 0, 0);
#pragma unroll
    for (int i = 0; i < 4; ++i) {
      float xv = xjs[(rowg*16 + q_*4 + i)*32 + u];
      accF[0][i] += xv * t0[i];
      accF[1][i] += xv * t1[i];
    }
    if (u + 1 < 30) {
      asm volatile("s_waitcnt vmcnt(0)" ::: "memory");
      __builtin_amdgcn_s_barrier();
      cur ^= 1;
    }
  }

#pragma unroll
  for (int nt = 0; nt < 2; ++nt)
#pragma unroll
    for (int i = 0; i < 4; ++i)
      mbuf[(rowg*16 + q_*4 + i)*64 + colg*32 + nt*16 + r_] = accF[nt][i];
  __syncthreads();

#pragma unroll 1
  for (int i = tid; i < 64*70; i += 512) {
    int e = i/70, c = i - e*70;
    float v;
    if (c < 40) v = mbuf[e*64 + c] * SH0C;
    else { int vv = (c - 40)/3, k = (c - 40) - vv*3; v = mbuf[e*64 + 40 + vv] * shls[e*3 + k]; }
    atomicAdd(&agg[(size_t)coll[e]*70 + c], v);
  }
}

// ---------------- TP layer 2 ----------------
__global__ __launch_bounds__(512, 2)
void tp2_kernel(const uint16_t* __restrict__ x3, const char* __restrict__ ws,
                const int* __restrict__ eidx, float* __restrict__ agg2)
{
  constexpr int P2 = 67;
  __shared__ float wbuf2[64 * P2];
  __shared__ float xjs[64*30];
  __shared__ float xjv[64*30];
  __shared__ float Db[64*10];
  __shared__ float shls[64*3];
  __shared__ int   rowl[64];
  __shared__ int   coll[64];

  const float* h2  = (const float*)(ws + OFF_H2);
  const float* shl = (const float*)(ws + OFF_SHL);
  const float* b4p = (const float*)(ws + OFF_B4P2);
  const bf16x8* __restrict__ bv4 = (const bf16x8*)(ws + OFF_W4P2);

  const int tid = threadIdx.x, lane = tid & 63, wv = tid >> 6;
  const int e0l = blockIdx.x * 64;
  const int r_ = lane & 15, q_ = lane >> 4;

  if (tid < 64) { rowl[tid] = eidx[e0l + tid]; coll[tid] = eidx[E_EDGES + e0l + tid]; }
  for (int i = tid; i < 192; i += 512) shls[i] = shl[(size_t)e0l*3 + i];
  __syncthreads();
  for (int i = tid; i < 64*60; i += 512) {
    int e = i/60, u = i - e*60;
    float v = h2[(size_t)rowl[e]*64 + u];
    if (u < 30) xjs[e*30 + u] = v; else xjv[e*30 + (u - 30)] = v;
  }
  __syncthreads();
  for (int i = tid; i < 640; i += 512) {
    int e = i/10, v = i - e*10;
    float d = 0.f;
#pragma unroll
    for (int m = 0; m < 3; ++m) d += xjv[e*30 + v*3 + m] * shls[e*3 + m];
    Db[i] = d * INV_SQRT3;
  }

  const int rbase = (wv >> 2)*2, nt4 = wv & 3;
  bf16x8 a4[2][2];
#pragma unroll
  for (int kk = 0; kk < 2; ++kk)
#pragma unroll
    for (int rbi = 0; rbi < 2; ++rbi) {
      int row = e0l + (rbase + rbi)*16 + r_;
      a4[kk][rbi] = *reinterpret_cast<const bf16x8*>((const char*)x3 + (size_t)row*128 + kk*64 + q_*16);
    }
  f32x4 acc[2];
  f32x4 zv = {0.f, 0.f, 0.f, 0.f};
  acc[0] = zv; acc[1] = zv;
#pragma unroll
  for (int kk = 0; kk < 2; ++kk) {
    bf16x8 b4 = bv4[(size_t)(kk*4 + nt4)*64 + lane];
#pragma unroll
    for (int rbi = 0; rbi < 2; ++rbi)
      acc[rbi] = __builtin_amdgcn_mfma_f32_16x16x32_bf16(a4[kk][rbi], b4, acc[rbi], 0, 0, 0);
  }
  __syncthreads();
  {
    int cg = nt4*16 + r_;
    float bs = b4p[cg];
#pragma unroll
    for (int rbi = 0; rbi < 2; ++rbi)
#pragma unroll
      for (int i2 = 0; i2 < 4; ++i2) {
        int e = (rbase + rbi)*16 + q_*4 + i2;
        wbuf2[e*P2 + cg] = acc[rbi][i2] + bs;
      }
  }
  __syncthreads();

  if (tid < 64) {
    int e = tid;
    float m = 0.f, m2 = 0.f;
#pragma unroll
    for (int c = 0; c < 30; ++c) m += xjs[e*30 + c] * wbuf2[e*P2 + c];
#pragma unroll
    for (int vv = 0; vv < 10; ++vv) m2 += Db[e*10 + vv] * wbuf2[e*P2 + 30 + vv];
    atomicAdd(&agg2[coll[e]], m * (SH0C * INV_SQRT30) + m2 * INV_SQRT10);
  }
}

// ---------------- node kernels ----------------
__global__ void node_mid(char* ws, const float* __restrict__ si1w)
{
  int nid = blockIdx.x * blockDim.x + threadIdx.x;
  if (nid >= N_NODES) return;
  const float* hN  = (const float*)(ws + OFF_HN)  + (size_t)nid*32;
  const float* agg = (const float*)(ws + OFF_AGG) + (size_t)nid*70;
  float* h2        = (float*)(ws + OFF_H2)        + (size_t)nid*64;

  float hn[30];
#pragma unroll
  for (int u = 0; u < 30; ++u) hn[u] = hN[u];

  float h1[70];
#pragma unroll 1
  for (int v = 0; v < 40; ++v) {
    float s = 0.f;
#pragma unroll
    for (int u = 0; u < 30; ++u) s += hn[u] * si1w[u*40 + v];
    h1[v] = SQ2C * (s + agg[v]);
  }
#pragma unroll
  for (int c = 40; c < 70; ++c) h1[c] = agg[c];

#pragma unroll
  for (int u = 0; u < 30; ++u) h2[u] = swishf(h1[u]);
#pragma unroll
  for (int v = 0; v < 10; ++v) {
    float g = 1.f / (1.f + __expf(-h1[30 + v]));
#pragma unroll
    for (int k = 0; k < 3; ++k) h2[30 + v*3 + k] = h1[40 + v*3 + k] * g;
  }
}

__global__ void node_final(char* ws, const float* __restrict__ si2w, const int* __restrict__ batch)
{
  __shared__ float ls[NGRAPH];
  if (threadIdx.x < NGRAPH) ls[threadIdx.x] = 0.f;
  __syncthreads();
  int nid = blockIdx.x * blockDim.x + threadIdx.x;
  if (nid < N_NODES) {
    const float* h2   = (const float*)(ws + OFF_H2) + (size_t)nid*64;
    const float* agg2 = (const float*)(ws + OFF_AGG2);
    float s2 = 0.f;
#pragma unroll
    for (int u = 0; u < 30; ++u) s2 += h2[u] * si2w[u];
    float val = SQ2C * (s2 * INV_SQRT30 + agg2[nid]);
    atomicAdd(&ls[batch[nid]], val);
  }
  __syncthreads();
  if (threadIdx.x < NGRAPH)
    atomicAdd(((float*)(ws + OFF_GSUM)) + threadIdx.x, ls[threadIdx.x]);
}

__global__ void write_out(const char* ws, float* out)
{
  int g = threadIdx.x;
  if (g < NGRAPH) out[g] = ((const float*)(ws + OFF_GSUM))[g];
}

// ---------------- launch ----------------
extern "C" void kernel_launch(void* const* d_in, const int* in_sizes, int n_in,
                              void* d_out, int out_size, void* d_ws, size_t ws_size,
                              hipStream_t stream)
{
  const float* pos  = (const float*)d_in[0];
  const float* emb  = (const float*)d_in[1];
  const float* si1w = (const float*)d_in[2];
  const float* si2w = (const float*)d_in[3];
  const float* w1a = (const float*)d_in[4];  const float* b1a = (const float*)d_in[5];
  const float* w2a = (const float*)d_in[6];  const float* b2a = (const float*)d_in[7];
  const float* w3a = (const float*)d_in[8];  const float* b3a = (const float*)d_in[9];
  const float* w4a = (const float*)d_in[10]; const float* b4a = (const float*)d_in[11];
  const float* w1b = (const float*)d_in[12]; const float* b1b = (const float*)d_in[13];
  const float* w2b = (const float*)d_in[14]; const float* b2b = (const float*)d_in[15];
  const float* w3b = (const float*)d_in[16]; const float* b3b = (const float*)d_in[17];
  const float* w4b = (const float*)d_in[18]; const float* b4b = (const float*)d_in[19];
  const int* z     = (const int*)d_in[20];
  const int* eidx  = (const int*)d_in[21];
  const int* batch = (const int*)d_in[22];
  char* ws = (char*)d_ws;

  uint16_t* basis = (uint16_t*)(ws + OFF_BAS);
  float*    shl   = (float*)(ws + OFF_SHL);
  uint16_t* x3    = (uint16_t*)(ws + OFF_X3);

  hipMemsetAsync(ws + OFF_AGG, 0, OFF_ZEND - OFF_AGG, stream);

  prep_kernel<<<1437, 256, 0, stream>>>(w1a, w2a, w3a, w4a, w1b, w2b, w3b, w4b,
                                        b1a, b2a, b3a, b4a, b1b, b2b, b3b, b4b,
                                        emb, z, ws);
  edge_meta<<<E_EDGES/256, 256, 0, stream>>>(pos, eidx, basis, shl);

  // ---- layer 1 ----
  fused_mlp<<<E_EDGES/64, 512, 0, stream>>>(basis,
      (const uint16_t*)(ws + OFF_W1P1), (const float*)(ws + OFF_B1P1),
      (const uint16_t*)(ws + OFF_W2P1), (const float*)(ws + OFF_B2P1),
      (const uint16_t*)(ws + OFF_W3P1), (const float*)(ws + OFF_B3P1), x3);
  tp1_gemm<<<E_EDGES/64, 512, 0, stream>>>(x3, ws, eidx, (float*)(ws + OFF_AGG));

  node_mid<<<N_NODES/256, 256, 0, stream>>>(ws, si1w);

  // ---- layer 2 ----
  fused_mlp<<<E_EDGES/64, 512, 0, stream>>>(basis,
      (const uint16_t*)(ws + OFF_W1P2), (const float*)(ws + OFF_B1P2),
      (const uint16_t*)(ws + OFF_W2P2), (const float*)(ws + OFF_B2P2),
      (const uint16_t*)(ws + OFF_W3P2), (const float*)(ws + OFF_B3P2), x3);
  tp2_kernel<<<E_EDGES/64, 512, 0, stream>>>(x3, ws, eidx, (float*)(ws + OFF_AGG2));

  node_final<<<N_NODES/256, 256, 0, stream>>>(ws, si2w, batch);
  write_out<<<1, 64, 0, stream>>>(ws, (float*)d_out);
}

// Round 24
// 526.994 us; speedup vs baseline: 1.4639x; 1.0112x over previous
//
#include <hip/hip_runtime.h>
#include <stdint.h>

typedef __attribute__((ext_vector_type(8))) short bf16x8;
typedef __attribute__((ext_vector_type(4))) float f32x4;

#define N_NODES 8192
#define E_EDGES 163840
#define NGRAPH  32

#define INV_SQRT30 0.18257419f
#define SH0C       0.22360680f   /* 1/sqrt(20) */
#define SQRT3C     1.73205081f
#define INV_SQRT3  0.57735027f
#define INV_SQRT10 0.31622777f
#define SQ2C       0.70710678f

// ---------------- workspace layout (bytes) ----------------
enum : unsigned {
  OFF_W1P1 = 0u,       OFF_W2P1 = 65536u,   OFF_W3P1 = 589824u,  OFF_W4P1 = 655360u,
  OFF_W1P2 = 851968u,  OFF_W2P2 = 917504u,  OFF_W3P2 = 1441792u, OFF_W4P2 = 1507328u,
  OFF_B1P1 = 1515520u, OFF_B2P1 = 1517568u, OFF_B3P1 = 1519616u, OFF_B4P1 = 1519872u,
  OFF_B1P2 = 1526016u, OFF_B2P2 = 1528064u, OFF_B3P2 = 1530112u, OFF_B4P2 = 1530368u,
  OFF_HN   = 1530624u, // [8192][32] f32
  OFF_H2   = 2579200u, // [8192][64] f32
  OFF_AGG  = 4676352u, // [8192][70] f32
  OFF_AGG2 = 6970112u, // [8192] f32
  OFF_GSUM = 7002880u, // [32] f32
  OFF_ZEND = 7003008u,
  OFF_SHL  = 7003136u,  // [E][3] f32
  OFF_BAS  = 8969216u,  // [E][64] bf16 (linear)
  OFF_W4N1 = 29940736u, // 30 x 8 x 1KB
  OFF_X3   = 30186496u  // [E][64] bf16
};

__device__ __forceinline__ uint16_t f2bf(float f){
  union { float f; uint32_t u; } v; v.f = f;
  uint32_t r = v.u + 0x7fffu + ((v.u >> 16) & 1u);
  return (uint16_t)(r >> 16);
}
__device__ __forceinline__ float swishf(float x){ return x / (1.f + __expf(-x)); }
__device__ __forceinline__ float swish_fast(float x){
  float d = 1.f + __expf(-x);
  return x * __builtin_amdgcn_rcpf(d);
}

// ---------------- weight pre-pack (f32 src -> bf16 MFMA B-fragment order) ----------------
__device__ __forceinline__ void pack_mat(const float* __restrict__ src, int K, int N, int NP,
                                         uint16_t* __restrict__ dst, int t)
{
  int lane = t & 63;
  int tile = t >> 6;
  int NT = NP >> 4;
  int nn = tile % NT, kk = tile / NT;
  int k0 = kk*32 + ((lane >> 4) << 3);
  int n  = nn*16 + (lane & 15);
  union { short s[8]; bf16x8 v; } tmp;
#pragma unroll
  for (int b = 0; b < 8; ++b) {
    int k = k0 + b;
    tmp.s[b] = (k < K && n < N) ? (short)f2bf(src[(size_t)k*N + n]) : (short)0;
  }
  *reinterpret_cast<bf16x8*>(dst + (size_t)t*8) = tmp.v;
}

// W4' pack for tp1-as-GEMM
__device__ __forceinline__ void pack_w4n(const float* __restrict__ w4, const float* __restrict__ b4,
                                         uint16_t* __restrict__ dst, int t)
{
  int lane = t & 63;
  int tile = t >> 6;           // 0..239
  int u = tile >> 3, j = tile & 7;
  int kk = j >> 2, nn = j & 3;
  int k0 = kk*32 + ((lane >> 4) << 3);
  int n  = nn*16 + (lane & 15);
  union { short s[8]; bf16x8 v; } tmp;
#pragma unroll
  for (int b = 0; b < 8; ++b) {
    int k = k0 + b;
    float val = 0.f;
    if (n < 50) {
      int cg = (n < 40) ? (u*40 + n) : (1200 + u*10 + (n - 40));
      if (k < 50) val = w4[(size_t)k*1500 + cg];
      else if (k == 63) val = b4[cg];
    }
    tmp.s[b] = (short)f2bf(val);
  }
  *reinterpret_cast<bf16x8*>(dst + (size_t)t*8) = tmp.v;
}

__global__ void prep_kernel(const float* w1a, const float* w2a, const float* w3a, const float* w4a,
                            const float* w1b, const float* w2b, const float* w3b, const float* w4b,
                            const float* b1a, const float* b2a, const float* b3a, const float* b4a,
                            const float* b1b, const float* b2b, const float* b3b, const float* b4b,
                            const float* emb, const int* z, char* ws)
{
  int t = blockIdx.x * 256 + threadIdx.x;
  if      (t < 4096)   pack_mat(w1a, 40, 500, 512,  (uint16_t*)(ws + OFF_W1P1), t);
  else if (t < 36864)  pack_mat(w2a, 500,500, 512,  (uint16_t*)(ws + OFF_W2P1), t - 4096);
  else if (t < 40960)  pack_mat(w3a, 500, 50, 64,   (uint16_t*)(ws + OFF_W3P1), t - 36864);
  else if (t < 45056)  { /* spare */ }
  else if (t < 49152)  pack_mat(w1b, 40, 500, 512,  (uint16_t*)(ws + OFF_W1P2), t - 45056);
  else if (t < 81920)  pack_mat(w2b, 500,500, 512,  (uint16_t*)(ws + OFF_W2P2), t - 49152);
  else if (t < 86016)  pack_mat(w3b, 500, 50, 64,   (uint16_t*)(ws + OFF_W3P2), t - 81920);
  else if (t < 86528)  pack_mat(w4b, 50,  40, 64,   (uint16_t*)(ws + OFF_W4P2), t - 86016);
  else if (t < 90304) {
    int loc = t - 86528;
    const float* src; float* dst; int realN;
    if      (loc < 512)  { src=b1a; dst=(float*)(ws+OFF_B1P1); realN=500; }
    else if (loc < 1024) { src=b2a; dst=(float*)(ws+OFF_B2P1); realN=500;  loc -= 512;  }
    else if (loc < 1088) { src=b3a; dst=(float*)(ws+OFF_B3P1); realN=50;   loc -= 1024; }
    else if (loc < 2624) { src=b4a; dst=(float*)(ws+OFF_B4P1); realN=1500; loc -= 1088; }
    else if (loc < 3136) { src=b1b; dst=(float*)(ws+OFF_B1P2); realN=500;  loc -= 2624; }
    else if (loc < 3648) { src=b2b; dst=(float*)(ws+OFF_B2P2); realN=500;  loc -= 3136; }
    else if (loc < 3712) { src=b3b; dst=(float*)(ws+OFF_B3P2); realN=50;   loc -= 3648; }
    else                 { src=b4b; dst=(float*)(ws+OFF_B4P2); realN=40;   loc -= 3712; }
    dst[loc] = (loc < realN) ? src[loc] : 0.f;
  }
  else if (t < 352448) {
    int i = t - 90304;
    int n = i >> 5, u = i & 31;
    float v = 0.f;
    if (u < 30) v = emb[(size_t)z[n]*30 + u] * INV_SQRT30;
    ((float*)(ws + OFF_HN))[i] = v;
  }
  else if (t < 367808) {
    pack_w4n(w4a, b4a, (uint16_t*)(ws + OFF_W4N1), t - 352448);
  }
}

// ---------------- edge meta ----------------
__global__ void edge_meta(const float* __restrict__ pos, const int* __restrict__ eidx,
                          uint16_t* __restrict__ basis, float* __restrict__ shl)
{
  int e = blockIdx.x * 256 + threadIdx.x;
  if (e >= E_EDGES) return;
  int rn = eidx[e], cn = eidx[E_EDGES + e];
  float ax = pos[rn*3+0] - pos[cn*3+0];
  float ay = pos[rn*3+1] - pos[cn*3+1];
  float az = pos[rn*3+2] - pos[cn*3+2];
  float rr = sqrtf(ax*ax + ay*ay + az*az + 1e-12f);
  float s = SQRT3C * SH0C / rr;
  shl[e*3+0] = ax*s; shl[e*3+1] = ay*s; shl[e*3+2] = az*s;
#pragma unroll
  for (int j = 0; j < 8; ++j) {
    union { short s[8]; bf16x8 v; } tmp;
#pragma unroll
    for (int b = 0; b < 8; ++b) {
      int c = j*8 + b;
      float vv = 0.f;
      if (c < 40) { float t = rr*3.9f - (float)c; vv = __expf(-t*t); }
      tmp.s[b] = (short)f2bf(vv);
    }
    *reinterpret_cast<bf16x8*>(basis + (size_t)e*64 + j*8) = tmp.v;
  }
}

// ---------------- fused MLP, 32-row tiles, (512,2), 2 blocks/CU target ----------------
__global__ __launch_bounds__(512, 2)
void fused_mlp(const uint16_t* __restrict__ basis,
               const uint16_t* __restrict__ W1p, const float* __restrict__ b1,
               const uint16_t* __restrict__ W2p, const float* __restrict__ b2,
               const uint16_t* __restrict__ W3p, const float* __restrict__ b3,
               uint16_t* __restrict__ x3)
{
  __shared__ __align__(16) char actb[32768];   // [32][512] bf16, XOR-swizzled

  const int tid = threadIdx.x, lane = tid & 63, wv = tid >> 6;
  const int m0 = blockIdx.x * 32;
  const int r = lane & 15, q = lane >> 4;

  const bf16x8* __restrict__ W1v = (const bf16x8*)W1p;
  const bf16x8* __restrict__ W2v = (const bf16x8*)W2p;
  const bf16x8* __restrict__ W3v = (const bf16x8*)W3p;

  f32x4 zv = {0.f, 0.f, 0.f, 0.f};
  const int colb2 = (wv*64 + r)*2;   // epilogue column byte base (nt adds 32)

  // ---- stage 1: act1 = swish(basis @ W1 + b1); A direct from global ----
  {
    f32x4 acc[2][4];
#pragma unroll
    for (int a = 0; a < 2; ++a)
#pragma unroll
      for (int c = 0; c < 4; ++c) acc[a][c] = zv;
#pragma unroll
    for (int ks = 0; ks < 2; ++ks) {
      bf16x8 af[2];
#pragma unroll
      for (int rb = 0; rb < 2; ++rb) {
        int row = m0 + rb*16 + r;
        af[rb] = *reinterpret_cast<const bf16x8*>((const char*)basis + (size_t)row*128 + ks*64 + q*16);
      }
      bf16x8 bfr[4];
#pragma unroll
      for (int j = 0; j < 4; ++j)
        bfr[j] = W1v[(size_t)((ks*32 + wv*4 + j)*64 + lane)];
#pragma unroll
      for (int j = 0; j < 4; ++j)
#pragma unroll
        for (int rb = 0; rb < 2; ++rb)
          acc[rb][j] = __builtin_amdgcn_mfma_f32_16x16x32_bf16(af[rb], bfr[j], acc[rb][j], 0, 0, 0);
    }
    float bsv[4];
#pragma unroll
    for (int nt = 0; nt < 4; ++nt) bsv[nt] = b1[wv*64 + nt*16 + r];
#pragma unroll
    for (int rb = 0; rb < 2; ++rb)
#pragma unroll
      for (int i = 0; i < 4; ++i) {
        int row = rb*16 + q*4 + i;
        int rowbase = row*1024;
        int mask = (row & 7) << 4;
#pragma unroll
        for (int nt = 0; nt < 4; ++nt)
          *(uint16_t*)(&actb[rowbase + ((colb2 + nt*32) ^ mask)]) = f2bf(swish_fast(acc[rb][nt][i] + bsv[nt]));
      }
  }
  __syncthreads();

  // ---- stage 2: act2 = swish(act1 @ W2 + b2) ----
  {
    f32x4 acc[2][4];
#pragma unroll
    for (int a = 0; a < 2; ++a)
#pragma unroll
      for (int c = 0; c < 4; ++c) acc[a][c] = zv;
#pragma unroll 2
    for (int ks = 0; ks < 16; ++ks) {
      bf16x8 af[2];
#pragma unroll
      for (int rb = 0; rb < 2; ++rb) {
        int row = rb*16 + r;
        int off = row*1024 + ((ks*64 + q*16) ^ ((row & 7) << 4));
        af[rb] = *reinterpret_cast<const bf16x8*>(&actb[off]);
      }
      bf16x8 bfr[4];
#pragma unroll
      for (int j = 0; j < 4; ++j)
        bfr[j] = W2v[(size_t)((ks*32 + wv*4 + j)*64 + lane)];
#pragma unroll
      for (int j = 0; j < 4; ++j)
#pragma unroll
        for (int rb = 0; rb < 2; ++rb)
          acc[rb][j] = __builtin_amdgcn_mfma_f32_16x16x32_bf16(af[rb], bfr[j], acc[rb][j], 0, 0, 0);
    }
    __syncthreads();   // all waves done READING act1
    float bsv[4];
#pragma unroll
    for (int nt = 0; nt < 4; ++nt) bsv[nt] = b2[wv*64 + nt*16 + r];
#pragma unroll
    for (int rb = 0; rb < 2; ++rb)
#pragma unroll
      for (int i = 0; i < 4; ++i) {
        int row = rb*16 + q*4 + i;
        int rowbase = row*1024;
        int mask = (row & 7) << 4;
#pragma unroll
        for (int nt = 0; nt < 4; ++nt)
          *(uint16_t*)(&actb[rowbase + ((colb2 + nt*32) ^ mask)]) = f2bf(swish_fast(acc[rb][nt][i] + bsv[nt]));
      }
  }
  __syncthreads();

  // ---- stage 3: x3 = swish(act2 @ W3 + b3), col63 := 1; wave = (rb, ntile) ----
  {
    const int rb3 = wv >> 2, nt3 = wv & 3;
    f32x4 acc1 = zv;
#pragma unroll 2
    for (int ks = 0; ks < 16; ++ks) {
      int row = rb3*16 + r;
      int off = row*1024 + ((ks*64 + q*16) ^ ((row & 7) << 4));
      bf16x8 a = *reinterpret_cast<const bf16x8*>(&actb[off]);
      bf16x8 bb = W3v[(size_t)((ks*4 + nt3)*64 + lane)];
      acc1 = __builtin_amdgcn_mfma_f32_16x16x32_bf16(a, bb, acc1, 0, 0, 0);
    }
    int col = nt3*16 + r;
    float bs = b3[col];
#pragma unroll
    for (int i = 0; i < 4; ++i) {
      int row = m0 + rb3*16 + q*4 + i;
      float v = swish_fast(acc1[i] + bs);
      if (col == 63) v = 1.f;
      x3[(size_t)row*64 + col] = f2bf(v);
    }
  }
}

// ---------------- TP layer 1 as scaled GEMM (no LDS staging, no u-loop barriers) ----------------
__global__ __launch_bounds__(512, 2)
void tp1_gemm(const uint16_t* __restrict__ x3, const char* __restrict__ ws,
              const int* __restrict__ eidx, float* __restrict__ agg)
{
  __shared__ float xjs[64*32];
  __shared__ float mbuf[64*64];
  __shared__ float shls[64*3];
  __shared__ int   rowl[64];
  __shared__ int   coll[64];

  const float* hN  = (const float*)(ws + OFF_HN);
  const float* shl = (const float*)(ws + OFF_SHL);
  const bf16x8* __restrict__ Wv = (const bf16x8*)(ws + OFF_W4N1);

  const int tid = threadIdx.x, lane = tid & 63, wv = tid >> 6;
  const int e0l = blockIdx.x * 64;
  const int r_ = lane & 15, q_ = lane >> 4;
  const int rowg = wv >> 1, colg = wv & 1;

  if (tid < 64) { rowl[tid] = eidx[e0l + tid]; coll[tid] = eidx[E_EDGES + e0l + tid]; }
  for (int i = tid; i < 192; i += 512) shls[i] = shl[(size_t)e0l*3 + i];
  __syncthreads();
  for (int i = tid; i < 64*32; i += 512) {
    int e = i >> 5, u = i & 31;
    xjs[i] = hN[(size_t)rowl[e]*32 + u];
  }

  bf16x8 a0, a1;
  {
    int row = e0l + rowg*16 + r_;
    const char* base = (const char*)x3 + (size_t)row*128 + q_*16;
    a0 = *reinterpret_cast<const bf16x8*>(base);
    a1 = *reinterpret_cast<const bf16x8*>(base + 64);
  }
  __syncthreads();   // xjs ready

  f32x4 zv = {0.f, 0.f, 0.f, 0.f};
  f32x4 accF[2];
  accF[0] = zv; accF[1] = zv;

  const size_t wbase = (size_t)(colg*2)*64 + lane;

#pragma unroll 2
  for (int u = 0; u < 30; ++u) {
    bf16x8 b00 = Wv[(size_t)(u*8 + 0)*64 + wbase];
    bf16x8 b01 = Wv[(size_t)(u*8 + 1)*64 + wbase];
    bf16x8 b10 = Wv[(size_t)(u*8 + 4)*64 + wbase];
    bf16x8 b11 = Wv[(size_t)(u*8 + 5)*64 + wbase];
    f32x4 t0 = __builtin_amdgcn_mfma_f32_16x16x32_bf16(a0, b00, zv, 0, 0, 0);
    t0 = __builtin_amdgcn_mfma_f32_16x16x32_bf16(a1, b10, t0, 0, 0, 0);
    f32x4 t1 = __builtin_amdgcn_mfma_f32_16x16x32_bf16(a0, b01, zv, 0, 0, 0);
    t1 = __builtin_amdgcn_mfma_f32_16x16x32_bf16(a1, b11, t1, 0, 0, 0);
#pragma unroll
    for (int i = 0; i < 4; ++i) {
      float xv = xjs[(rowg*16 + q_*4 + i)*32 + u];
      accF[0][i] += xv * t0[i];
      accF[1][i] += xv * t1[i];
    }
  }

#pragma unroll
  for (int nt = 0; nt < 2; ++nt)
#pragma unroll
    for (int i = 0; i < 4; ++i)
      mbuf[(rowg*16 + q_*4 + i)*64 + colg*32 + nt*16 + r_] = accF[nt][i];
  __syncthreads();

#pragma unroll 1
  for (int i = tid; i < 64*70; i += 512) {
    int e = i/70, c = i - e*70;
    float v;
    if (c < 40) v = mbuf[e*64 + c] * SH0C;
    else { int vv = (c - 40)/3, k = (c - 40) - vv*3; v = mbuf[e*64 + 40 + vv] * shls[e*3 + k]; }
    atomicAdd(&agg[(size_t)coll[e]*70 + c], v);
  }
}

// ---------------- TP layer 2 ----------------
__global__ __launch_bounds__(512, 2)
void tp2_kernel(const uint16_t* __restrict__ x3, const char* __restrict__ ws,
                const int* __restrict__ eidx, float* __restrict__ agg2)
{
  constexpr int P2 = 67;
  __shared__ float wbuf2[64 * P2];
  __shared__ float xjs[64*30];
  __shared__ float xjv[64*30];
  __shared__ float Db[64*10];
  __shared__ float shls[64*3];
  __shared__ int   rowl[64];
  __shared__ int   coll[64];

  const float* h2  = (const float*)(ws + OFF_H2);
  const float* shl = (const float*)(ws + OFF_SHL);
  const float* b4p = (const float*)(ws + OFF_B4P2);
  const bf16x8* __restrict__ bv4 = (const bf16x8*)(ws + OFF_W4P2);

  const int tid = threadIdx.x, lane = tid & 63, wv = tid >> 6;
  const int e0l = blockIdx.x * 64;
  const int r_ = lane & 15, q_ = lane >> 4;

  if (tid < 64) { rowl[tid] = eidx[e0l + tid]; coll[tid] = eidx[E_EDGES + e0l + tid]; }
  for (int i = tid; i < 192; i += 512) shls[i] = shl[(size_t)e0l*3 + i];
  __syncthreads();
  for (int i = tid; i < 64*60; i += 512) {
    int e = i/60, u = i - e*60;
    float v = h2[(size_t)rowl[e]*64 + u];
    if (u < 30) xjs[e*30 + u] = v; else xjv[e*30 + (u - 30)] = v;
  }
  __syncthreads();
  for (int i = tid; i < 640; i += 512) {
    int e = i/10, v = i - e*10;
    float d = 0.f;
#pragma unroll
    for (int m = 0; m < 3; ++m) d += xjv[e*30 + v*3 + m] * shls[e*3 + m];
    Db[i] = d * INV_SQRT3;
  }

  const int rbase = (wv >> 2)*2, nt4 = wv & 3;
  bf16x8 a4[2][2];
#pragma unroll
  for (int kk = 0; kk < 2; ++kk)
#pragma unroll
    for (int rbi = 0; rbi < 2; ++rbi) {
      int row = e0l + (rbase + rbi)*16 + r_;
      a4[kk][rbi] = *reinterpret_cast<const bf16x8*>((const char*)x3 + (size_t)row*128 + kk*64 + q_*16);
    }
  f32x4 acc[2];
  f32x4 zv = {0.f, 0.f, 0.f, 0.f};
  acc[0] = zv; acc[1] = zv;
#pragma unroll
  for (int kk = 0; kk < 2; ++kk) {
    bf16x8 b4 = bv4[(size_t)(kk*4 + nt4)*64 + lane];
#pragma unroll
    for (int rbi = 0; rbi < 2; ++rbi)
      acc[rbi] = __builtin_amdgcn_mfma_f32_16x16x32_bf16(a4[kk][rbi], b4, acc[rbi], 0, 0, 0);
  }
  __syncthreads();
  {
    int cg = nt4*16 + r_;
    float bs = b4p[cg];
#pragma unroll
    for (int rbi = 0; rbi < 2; ++rbi)
#pragma unroll
      for (int i2 = 0; i2 < 4; ++i2) {
        int e = (rbase + rbi)*16 + q_*4 + i2;
        wbuf2[e*P2 + cg] = acc[rbi][i2] + bs;
      }
  }
  __syncthreads();

  if (tid < 64) {
    int e = tid;
    float m = 0.f, m2 = 0.f;
#pragma unroll
    for (int c = 0; c < 30; ++c) m += xjs[e*30 + c] * wbuf2[e*P2 + c];
#pragma unroll
    for (int vv = 0; vv < 10; ++vv) m2 += Db[e*10 + vv] * wbuf2[e*P2 + 30 + vv];
    atomicAdd(&agg2[coll[e]], m * (SH0C * INV_SQRT30) + m2 * INV_SQRT10);
  }
}

// ---------------- node kernels ----------------
__global__ void node_mid(char* ws, const float* __restrict__ si1w)
{
  int nid = blockIdx.x * blockDim.x + threadIdx.x;
  if (nid >= N_NODES) return;
  const float* hN  = (const float*)(ws + OFF_HN)  + (size_t)nid*32;
  const float* agg = (const float*)(ws + OFF_AGG) + (size_t)nid*70;
  float* h2        = (float*)(ws + OFF_H2)        + (size_t)nid*64;

  float hn[30];
#pragma unroll
  for (int u = 0; u < 30; ++u) hn[u] = hN[u];

  float h1[70];
#pragma unroll 1
  for (int v = 0; v < 40; ++v) {
    float s = 0.f;
#pragma unroll
    for (int u = 0; u < 30; ++u) s += hn[u] * si1w[u*40 + v];
    h1[v] = SQ2C * (s + agg[v]);
  }
#pragma unroll
  for (int c = 40; c < 70; ++c) h1[c] = agg[c];

#pragma unroll
  for (int u = 0; u < 30; ++u) h2[u] = swishf(h1[u]);
#pragma unroll
  for (int v = 0; v < 10; ++v) {
    float g = 1.f / (1.f + __expf(-h1[30 + v]));
#pragma unroll
    for (int k = 0; k < 3; ++k) h2[30 + v*3 + k] = h1[40 + v*3 + k] * g;
  }
}

__global__ void node_final(char* ws, const float* __restrict__ si2w, const int* __restrict__ batch)
{
  __shared__ float ls[NGRAPH];
  if (threadIdx.x < NGRAPH) ls[threadIdx.x] = 0.f;
  __syncthreads();
  int nid = blockIdx.x * blockDim.x + threadIdx.x;
  if (nid < N_NODES) {
    const float* h2   = (const float*)(ws + OFF_H2) + (size_t)nid*64;
    const float* agg2 = (const float*)(ws + OFF_AGG2);
    float s2 = 0.f;
#pragma unroll
    for (int u = 0; u < 30; ++u) s2 += h2[u] * si2w[u];
    float val = SQ2C * (s2 * INV_SQRT30 + agg2[nid]);
    atomicAdd(&ls[batch[nid]], val);
  }
  __syncthreads();
  if (threadIdx.x < NGRAPH)
    atomicAdd(((float*)(ws + OFF_GSUM)) + threadIdx.x, ls[threadIdx.x]);
}

__global__ void write_out(const char* ws, float* out)
{
  int g = threadIdx.x;
  if (g < NGRAPH) out[g] = ((const float*)(ws + OFF_GSUM))[g];
}

// ---------------- launch ----------------
extern "C" void kernel_launch(void* const* d_in, const int* in_sizes, int n_in,
                              void* d_out, int out_size, void* d_ws, size_t ws_size,
                              hipStream_t stream)
{
  const float* pos  = (const float*)d_in[0];
  const float* emb  = (const float*)d_in[1];
  const float* si1w = (const float*)d_in[2];
  const float* si2w = (const float*)d_in[3];
  const float* w1a = (const float*)d_in[4];  const float* b1a = (const float*)d_in[5];
  const float* w2a = (const float*)d_in[6];  const float* b2a = (const float*)d_in[7];
  const float* w3a = (const float*)d_in[8];  const float* b3a = (const float*)d_in[9];
  const float* w4a = (const float*)d_in[10]; const float* b4a = (const float*)d_in[11];
  const float* w1b = (const float*)d_in[12]; const float* b1b = (const float*)d_in[13];
  const float* w2b = (const float*)d_in[14]; const float* b2b = (const float*)d_in[15];
  const float* w3b = (const float*)d_in[16]; const float* b3b = (const float*)d_in[17];
  const float* w4b = (const float*)d_in[18]; const float* b4b = (const float*)d_in[19];
  const int* z     = (const int*)d_in[20];
  const int* eidx  = (const int*)d_in[21];
  const int* batch = (const int*)d_in[22];
  char* ws = (char*)d_ws;

  uint16_t* basis = (uint16_t*)(ws + OFF_BAS);
  float*    shl   = (float*)(ws + OFF_SHL);
  uint16_t* x3    = (uint16_t*)(ws + OFF_X3);

  hipMemsetAsync(ws + OFF_AGG, 0, OFF_ZEND - OFF_AGG, stream);

  prep_kernel<<<1437, 256, 0, stream>>>(w1a, w2a, w3a, w4a, w1b, w2b, w3b, w4b,
                                        b1a, b2a, b3a, b4a, b1b, b2b, b3b, b4b,
                                        emb, z, ws);
  edge_meta<<<E_EDGES/256, 256, 0, stream>>>(pos, eidx, basis, shl);

  // ---- layer 1 ----
  fused_mlp<<<E_EDGES/32, 512, 0, stream>>>(basis,
      (const uint16_t*)(ws + OFF_W1P1), (const float*)(ws + OFF_B1P1),
      (const uint16_t*)(ws + OFF_W2P1), (const float*)(ws + OFF_B2P1),
      (const uint16_t*)(ws + OFF_W3P1), (const float*)(ws + OFF_B3P1), x3);
  tp1_gemm<<<E_EDGES/64, 512, 0, stream>>>(x3, ws, eidx, (float*)(ws + OFF_AGG));

  node_mid<<<N_NODES/256, 256, 0, stream>>>(ws, si1w);

  // ---- layer 2 ----
  fused_mlp<<<E_EDGES/32, 512, 0, stream>>>(basis,
      (const uint16_t*)(ws + OFF_W1P2), (const float*)(ws + OFF_B1P2),
      (const uint16_t*)(ws + OFF_W2P2), (const float*)(ws + OFF_B2P2),
      (const uint16_t*)(ws + OFF_W3P2), (const float*)(ws + OFF_B3P2), x3);
  tp2_kernel<<<E_EDGES/64, 512, 0, stream>>>(x3, ws, eidx, (float*)(ws + OFF_AGG2));

  node_final<<<N_NODES/256, 256, 0, stream>>>(ws, si2w, batch);
  write_out<<<1, 64, 0, stream>>>(ws, (float*)d_out);
}